// Round 1
// 796.119 us; speedup vs baseline: 2.0230x; 2.0230x over previous
//
#include <hip/hip_runtime.h>
#include <cstdint>
#include <cmath>

// Problem constants
#define B_   4
#define L_   2048
#define H_   2048
#define NH_  16
#define HD_  128
#define ML_  (B_*L_)   // 8192 rows total

using short8 = __attribute__((ext_vector_type(8))) short;
using f32x4  = __attribute__((ext_vector_type(4))) float;

__device__ inline short f2bf(float f){
  unsigned u = __builtin_bit_cast(unsigned, f);
  unsigned r = u + 0x7FFFu + ((u >> 16) & 1u);   // RNE
  return (short)(r >> 16);
}
__device__ inline float bf2f(short s){
  unsigned u = ((unsigned)(unsigned short)s) << 16;
  return __builtin_bit_cast(float, u);
}

// async global->LDS, 16B per lane, wave-uniform LDS base + lane*16
#define GLD16(gp, lp) __builtin_amdgcn_global_load_lds(                      \
    (const __attribute__((address_space(1))) void*)(gp),                     \
    (__attribute__((address_space(3))) void*)(lp), 16, 0, 0)

// ---------------------------------------------------------------------------
// RoPE cos/sin table: [2048][64] each, f32
// ---------------------------------------------------------------------------
__global__ void rope_table(float* __restrict__ cosT, float* __restrict__ sinT){
  int idx = blockIdx.x * 256 + threadIdx.x;
  if (idx >= L_ * 64) return;
  int l = idx >> 6, d = idx & 63;
  float invf = powf(10000.0f, -(float)d * (1.0f/64.0f));
  float fr = (float)l * invf;
  cosT[idx] = cosf(fr);
  sinT[idx] = sinf(fr);
}

// ---------------------------------------------------------------------------
// f32 -> bf16 elementwise (vectorized 8/thread)
// ---------------------------------------------------------------------------
__global__ __launch_bounds__(256)
void cvt_bf16(const float* __restrict__ in, short* __restrict__ out, int n8){
  int i = blockIdx.x * 256 + threadIdx.x;
  if (i >= n8) return;
  const float4* p = (const float4*)(in + (size_t)i * 8);
  float4 a = p[0], b = p[1];
  short8 s;
  s[0]=f2bf(a.x); s[1]=f2bf(a.y); s[2]=f2bf(a.z); s[3]=f2bf(a.w);
  s[4]=f2bf(b.x); s[5]=f2bf(b.y); s[6]=f2bf(b.z); s[7]=f2bf(b.w);
  *(short8*)(out + (size_t)i * 8) = s;
}

// ---------------------------------------------------------------------------
// GEMM: C[M,N] = A[M,K] @ B^T, A/B bf16, B is [N,K] row-major.
// 128x128 tile, BK=64, 256 threads (4 waves). m97 structure:
// global_load_lds width=16 into linear LDS, with pre-swizzled global source
// (slot = c4 ^ (row&7)) and the same swizzle on the ds_read side (rule #21).
// ---------------------------------------------------------------------------
template<int OUT_F32>
__global__ __launch_bounds__(256)
void gemm_bt_bf16(const short* __restrict__ A, const short* __restrict__ Bw,
                  void* __restrict__ Cp, int M, int N, int K)
{
  __shared__ short sA[128 * 64];   // linear, swizzle handled via source+read
  __shared__ short sB[128 * 64];
  const int tid  = threadIdx.x;
  const int lane = tid & 63;
  const int wave = tid >> 6;
  const int wr = wave >> 1, wc = wave & 1;
  const int ln = lane & 15, g = lane >> 4;

  // XCD-aware bijective remap; grid is fixed (16, 64) => nwg = 1024, %8==0
  int flat = blockIdx.y * gridDim.x + blockIdx.x;
  int wg   = (flat & 7) * 128 + (flat >> 3);
  const int m0 = (wg >> 4) * 128, n0 = (wg & 15) * 128;

  // per-lane pre-swizzled global 16B-slot:  lane covers (row8=lane>>3, slot=lane&7)
  const int lrow = lane >> 3;             // row within 8-row group (= row&7)
  const int lc4  = (lane & 7) ^ lrow;     // global column slot that lands here

  f32x4 acc[4][4];
  #pragma unroll
  for (int i = 0; i < 4; i++)
    #pragma unroll
    for (int j = 0; j < 4; j++) acc[i][j] = {0.f, 0.f, 0.f, 0.f};

  for (int k0 = 0; k0 < K; k0 += 64) {
    // stage A and B tiles (128 rows x 64 cols bf16 = 16KB each): 16+16 gl_lds
    #pragma unroll
    for (int i = 0; i < 4; i++) {
      int u = wave * 4 + i;               // 0..15, 8 rows each
      const short* ga = A  + (size_t)(m0 + u * 8 + lrow) * K + k0 + lc4 * 8;
      GLD16(ga, sA + u * 512);
      const short* gb = Bw + (size_t)(n0 + u * 8 + lrow) * K + k0 + lc4 * 8;
      GLD16(gb, sB + u * 512);
    }
    __syncthreads();   // compiler emits vmcnt(0) drain before barrier

    #pragma unroll
    for (int kk = 0; kk < 64; kk += 32) {
      short8 af[4], bfr[4];
      #pragma unroll
      for (int m = 0; m < 4; m++) {
        int row  = wr * 64 + m * 16 + ln;
        int slot = ((kk >> 3) + g) ^ (ln & 7);     // row&7 == ln&7
        af[m] = *(const short8*)(sA + row * 64 + slot * 8);
      }
      #pragma unroll
      for (int n = 0; n < 4; n++) {
        int row  = wc * 64 + n * 16 + ln;
        int slot = ((kk >> 3) + g) ^ (ln & 7);
        bfr[n] = *(const short8*)(sB + row * 64 + slot * 8);
      }
      #pragma unroll
      for (int m = 0; m < 4; m++)
        #pragma unroll
        for (int n = 0; n < 4; n++)
          acc[m][n] = __builtin_amdgcn_mfma_f32_16x16x32_bf16(af[m], bfr[n], acc[m][n], 0, 0, 0);
    }
    __syncthreads();
  }

  // epilogue: C/D layout col=lane&15, row=(lane>>4)*4+reg
  #pragma unroll
  for (int m = 0; m < 4; m++)
    #pragma unroll
    for (int n = 0; n < 4; n++)
      #pragma unroll
      for (int r = 0; r < 4; r++) {
        int row = m0 + wr * 64 + m * 16 + g * 4 + r;
        int col = n0 + wc * 64 + n * 16 + ln;
        float v = acc[m][n][r];
        if constexpr (OUT_F32) ((float*)Cp)[(size_t)row * N + col] = v;
        else                   ((short*)Cp)[(size_t)row * N + col] = f2bf(v);
      }
}

// ---------------------------------------------------------------------------
// RoPE apply, in place on bf16 Q (z=0, scaled by 1/sqrt(128)) and K (z=1).
// ---------------------------------------------------------------------------
__global__ __launch_bounds__(256)
void rope_apply(short* __restrict__ Qb, short* __restrict__ Kb,
                const float* __restrict__ cosT, const float* __restrict__ sinT)
{
  int idx = blockIdx.x * 256 + threadIdx.x;
  int z = blockIdx.y;
  short* ptr  = z ? Kb : Qb;
  float scale = z ? 1.0f : 0.08838834764831845f;
  int row = idx >> 7;
  int rem = idx & 127;
  int h = rem >> 3, ch = rem & 7;
  int l = row & (L_ - 1);
  short* base = ptr + (size_t)row * H_ + h * HD_ + ch * 8;
  short8 lo = *(short8*)base;
  short8 hi = *(short8*)(base + 64);
  const float* cp = cosT + l * 64 + ch * 8;
  const float* sp = sinT + l * 64 + ch * 8;
  short8 nlo, nhi;
  #pragma unroll
  for (int j = 0; j < 8; j++) {
    float c = cp[j], s = sp[j];
    float x0 = bf2f(lo[j]), x1 = bf2f(hi[j]);
    nlo[j] = f2bf((x0 * c - x1 * s) * scale);
    nhi[j] = f2bf((x1 * c + x0 * s) * scale);
  }
  *(short8*)base        = nlo;
  *(short8*)(base + 64) = nhi;
}

// ---------------------------------------------------------------------------
// Flash attention (causal). Same structure as before; the change is LDS
// bank-conflict elimination:
//  - lds_vt: kv index XOR-swizzled by ((d>>3)&7)<<3  -> transpose scalar
//    writes drop from ~32-way to ~4-way; b128 reads stay conflict-free.
//  - lds_p:  kv index XOR-swizzled by (q&8)<<1 -> breaks q / q+8 bank
//    collision (rows 8 apart alias: 36*8 dwords == 0 mod 32).
//  (lds_k pad-136 layout measured conflict-free per bank arithmetic: 4*ln
//   spread per 16-lane quarter — unchanged.)
// ---------------------------------------------------------------------------
__global__ __launch_bounds__(256)
void flash_attn(const short* __restrict__ Qb, const short* __restrict__ Kb,
                const short* __restrict__ Vb, short* __restrict__ AO)
{
  __shared__ short lds_k[64][136];      // [kv][d], pad 8
  __shared__ short lds_vt[128][72];     // [d][kv^swz], pad 8
  __shared__ short lds_p[4][16][72];    // per wave [qrow][kv^swz]

  const int blk = blockIdx.x;
  const int qt = blk & 31;
  const int bh = blk >> 5;
  const int h = bh & (NH_ - 1), b = bh >> 4;
  const int q0 = qt * 64;
  const int tid = threadIdx.x, wave = tid >> 6, lane = tid & 63;
  const int g = lane >> 4, ln = lane & 15;
  const size_t rowbase = (size_t)b * L_;
  const int colbase = h * HD_;

  short8 aq[4];
  {
    const short* qp = Qb + (rowbase + q0 + wave * 16 + ln) * H_ + colbase + g * 8;
    #pragma unroll
    for (int c = 0; c < 4; c++) aq[c] = *(const short8*)(qp + c * 32);
  }

  f32x4 acc_o[8];
  #pragma unroll
  for (int i = 0; i < 8; i++) acc_o[i] = {0.f, 0.f, 0.f, 0.f};
  float mrow[4], lrow[4];
  #pragma unroll
  for (int r = 0; r < 4; r++) { mrow[r] = -__builtin_inff(); lrow[r] = 0.f; }

  for (int t = 0; t <= qt; ++t) {
    const int k0 = t * 64;
    // ---- stage K tile and V^T tile ----
    #pragma unroll
    for (int i = 0; i < 4; i++) {
      int u = tid + i * 256;          // 1024 units: 64 rows x 16 chunks
      int row = u >> 4, ch = u & 15;
      const short* kp = Kb + (rowbase + k0 + row) * H_ + colbase + ch * 8;
      *(short8*)&lds_k[row][ch * 8] = *(const short8*)kp;
      const short* vp = Vb + (rowbase + k0 + row) * H_ + colbase + ch * 8;
      short8 vv = *(const short8*)vp;
      int vswz = (ch & 7) << 3;       // ((d>>3)&7)<<3 with d = ch*8+j
      #pragma unroll
      for (int j = 0; j < 8; j++) lds_vt[ch * 8 + j][row ^ vswz] = vv[j];
    }
    __syncthreads();

    // ---- S = Q K^T  (16 q rows x 64 kv) ----
    f32x4 sacc[4];
    #pragma unroll
    for (int nsub = 0; nsub < 4; nsub++) {
      f32x4 a = {0.f, 0.f, 0.f, 0.f};
      #pragma unroll
      for (int c = 0; c < 4; c++) {
        short8 bk = *(const short8*)&lds_k[nsub * 16 + ln][c * 32 + g * 8];
        a = __builtin_amdgcn_mfma_f32_16x16x32_bf16(aq[c], bk, a, 0, 0, 0);
      }
      sacc[nsub] = a;
    }
    // causal mask (only diagonal tile is partial)
    if (t == qt) {
      #pragma unroll
      for (int nsub = 0; nsub < 4; nsub++) {
        int kvloc = nsub * 16 + ln;
        #pragma unroll
        for (int r = 0; r < 4; r++) {
          int qloc = wave * 16 + g * 4 + r;
          if (kvloc > qloc) sacc[nsub][r] = -__builtin_inff();
        }
      }
    }
    // ---- online softmax ----
    f32x4 mx = sacc[0];
    #pragma unroll
    for (int nsub = 1; nsub < 4; nsub++)
      #pragma unroll
      for (int r = 0; r < 4; r++) mx[r] = fmaxf(mx[r], sacc[nsub][r]);
    #pragma unroll
    for (int r = 0; r < 4; r++) {
      float v = mx[r];
      v = fmaxf(v, __shfl_xor(v, 1));
      v = fmaxf(v, __shfl_xor(v, 2));
      v = fmaxf(v, __shfl_xor(v, 4));
      v = fmaxf(v, __shfl_xor(v, 8));
      mx[r] = v;
    }
    float f_[4];
    #pragma unroll
    for (int r = 0; r < 4; r++) {
      float mnew = fmaxf(mrow[r], mx[r]);
      f_[r] = __expf(mrow[r] - mnew);
      mrow[r] = mnew;
    }
    f32x4 psum = {0.f, 0.f, 0.f, 0.f};
    #pragma unroll
    for (int nsub = 0; nsub < 4; nsub++)
      #pragma unroll
      for (int r = 0; r < 4; r++) {
        float p = __expf(sacc[nsub][r] - mrow[r]);
        psum[r] += p;
        int q = g * 4 + r;
        lds_p[wave][q][(nsub * 16 + ln) ^ ((q & 8) << 1)] = f2bf(p);
      }
    #pragma unroll
    for (int r = 0; r < 4; r++) {
      float v = psum[r];
      v += __shfl_xor(v, 1);
      v += __shfl_xor(v, 2);
      v += __shfl_xor(v, 4);
      v += __shfl_xor(v, 8);
      lrow[r] = lrow[r] * f_[r] + v;
    }
    // rescale O
    #pragma unroll
    for (int d = 0; d < 8; d++)
      #pragma unroll
      for (int r = 0; r < 4; r++) acc_o[d][r] *= f_[r];
    __syncthreads();   // lds_p visible (and staging reads done)

    // ---- O += P V ----
    int pswz = (ln & 8) << 1;          // (q&8)<<1 with q = ln
    short8 pa0 = *(const short8*)&lds_p[wave][ln][(g * 8) ^ pswz];
    short8 pa1 = *(const short8*)&lds_p[wave][ln][(32 + g * 8) ^ pswz];
    #pragma unroll
    for (int d = 0; d < 8; d++) {
      int vswz = ((d * 2 + (ln >> 3)) & 7) << 3;   // ((d'>>3)&7)<<3, d' = d*16+ln
      short8 vb0 = *(const short8*)&lds_vt[d * 16 + ln][(g * 8) ^ vswz];
      short8 vb1 = *(const short8*)&lds_vt[d * 16 + ln][(32 + g * 8) ^ vswz];
      acc_o[d] = __builtin_amdgcn_mfma_f32_16x16x32_bf16(pa0, vb0, acc_o[d], 0, 0, 0);
      acc_o[d] = __builtin_amdgcn_mfma_f32_16x16x32_bf16(pa1, vb1, acc_o[d], 0, 0, 0);
    }
    __syncthreads();   // PV reads done before next tile's staging
  }

  // ---- write O / l ----
  #pragma unroll
  for (int r = 0; r < 4; r++) {
    float inv = 1.0f / lrow[r];
    int qrow = q0 + wave * 16 + g * 4 + r;
    short* op = AO + (rowbase + qrow) * H_ + colbase;
    #pragma unroll
    for (int d = 0; d < 8; d++)
      op[d * 16 + ln] = f2bf(acc_o[d][r] * inv);
  }
}

// ---------------------------------------------------------------------------
extern "C" void kernel_launch(void* const* d_in, const int* in_sizes, int n_in,
                              void* d_out, int out_size, void* d_ws, size_t ws_size,
                              hipStream_t stream)
{
  const float* x  = (const float*)d_in[0];
  // d_in[1] = mask (tril causal) — implemented analytically
  const float* Wq = (const float*)d_in[2];
  const float* Wk = (const float*)d_in[3];
  const float* Wv = (const float*)d_in[4];
  const float* Wo = (const float*)d_in[5];
  float* out = (float*)d_out;

  char* ws = (char*)d_ws;
  const size_t SZ = (size_t)ML_ * H_ * sizeof(short);  // 32 MiB
  short* Qb = (short*)(ws);
  short* Kb = (short*)(ws + SZ);
  short* Vb = (short*)(ws + 2 * SZ);
  short* xb = (short*)(ws + 3 * SZ);   // x in bf16; dead after V-GEMM
  short* AO = xb;                      // alias (in-order stream: safe)
  short* Wb = (short*)(ws + 4 * SZ);   // 8 MiB, reused per weight
  float* cosT = (float*)(ws + 4 * SZ + (size_t)H_ * H_ * sizeof(short));
  float* sinT = cosT + (size_t)L_ * 64;

  rope_table<<<512, 256, 0, stream>>>(cosT, sinT);

  // pre-convert activations/weights to bf16 (identical RNE as before)
  cvt_bf16<<<ML_ * H_ / 8 / 256, 256, 0, stream>>>(x, xb, ML_ * H_ / 8);

  dim3 gg(H_ / 128, ML_ / 128);   // (16, 64)
  cvt_bf16<<<H_ * H_ / 8 / 256, 256, 0, stream>>>(Wq, Wb, H_ * H_ / 8);
  gemm_bt_bf16<0><<<gg, 256, 0, stream>>>(xb, Wb, Qb, ML_, H_, H_);
  cvt_bf16<<<H_ * H_ / 8 / 256, 256, 0, stream>>>(Wk, Wb, H_ * H_ / 8);
  gemm_bt_bf16<0><<<gg, 256, 0, stream>>>(xb, Wb, Kb, ML_, H_, H_);
  cvt_bf16<<<H_ * H_ / 8 / 256, 256, 0, stream>>>(Wv, Wb, H_ * H_ / 8);
  gemm_bt_bf16<0><<<gg, 256, 0, stream>>>(xb, Wb, Vb, ML_, H_, H_);

  rope_apply<<<dim3(ML_ * NH_ * 8 / 256, 2), 256, 0, stream>>>(Qb, Kb, cosT, sinT);

  flash_attn<<<B_ * NH_ * (L_ / 64), 256, 0, stream>>>(Qb, Kb, Vb, AO);

  cvt_bf16<<<H_ * H_ / 8 / 256, 256, 0, stream>>>(Wo, Wb, H_ * H_ / 8);
  gemm_bt_bf16<1><<<gg, 256, 0, stream>>>(AO, Wb, out, ML_, H_, H_);
}

// Round 2
// 715.163 us; speedup vs baseline: 2.2520x; 1.1132x over previous
//
#include <hip/hip_runtime.h>
#include <cstdint>
#include <cmath>

// Problem constants
#define B_   4
#define L_   2048
#define H_   2048
#define NH_  16
#define HD_  128
#define ML_  (B_*L_)   // 8192 rows total

using short8 = __attribute__((ext_vector_type(8))) short;
using f32x4  = __attribute__((ext_vector_type(4))) float;

__device__ inline short f2bf(float f){
  unsigned u = __builtin_bit_cast(unsigned, f);
  unsigned r = u + 0x7FFFu + ((u >> 16) & 1u);   // RNE
  return (short)(r >> 16);
}
__device__ inline float bf2f(short s){
  unsigned u = ((unsigned)(unsigned short)s) << 16;
  return __builtin_bit_cast(float, u);
}

// async global->LDS, 16B per lane, wave-uniform LDS base + lane*16
#define GLD16(gp, lp) __builtin_amdgcn_global_load_lds(                      \
    (const __attribute__((address_space(1))) void*)(gp),                     \
    (__attribute__((address_space(3))) void*)(lp), 16, 0, 0)

// ---------------------------------------------------------------------------
// RoPE cos/sin table: [2048][64] each, f32
// ---------------------------------------------------------------------------
__global__ void rope_table(float* __restrict__ cosT, float* __restrict__ sinT){
  int idx = blockIdx.x * 256 + threadIdx.x;
  if (idx >= L_ * 64) return;
  int l = idx >> 6, d = idx & 63;
  float invf = powf(10000.0f, -(float)d * (1.0f/64.0f));
  float fr = (float)l * invf;
  cosT[idx] = cosf(fr);
  sinT[idx] = sinf(fr);
}

// ---------------------------------------------------------------------------
// f32 -> bf16 elementwise (vectorized 8/thread)
// ---------------------------------------------------------------------------
__global__ __launch_bounds__(256)
void cvt_bf16(const float* __restrict__ in, short* __restrict__ out, int n8){
  int i = blockIdx.x * 256 + threadIdx.x;
  if (i >= n8) return;
  const float4* p = (const float4*)(in + (size_t)i * 8);
  float4 a = p[0], b = p[1];
  short8 s;
  s[0]=f2bf(a.x); s[1]=f2bf(a.y); s[2]=f2bf(a.z); s[3]=f2bf(a.w);
  s[4]=f2bf(b.x); s[5]=f2bf(b.y); s[6]=f2bf(b.z); s[7]=f2bf(b.w);
  *(short8*)(out + (size_t)i * 8) = s;
}

// ---------------------------------------------------------------------------
// GEMM: C[M,N] = A[M,K] @ B^T, A/B bf16, B is [N,K] row-major.
// 128x128 tile, BK=64, 256 threads (4 waves). m97 structure, unchanged.
// ---------------------------------------------------------------------------
template<int OUT_F32>
__global__ __launch_bounds__(256)
void gemm_bt_bf16(const short* __restrict__ A, const short* __restrict__ Bw,
                  void* __restrict__ Cp, int M, int N, int K)
{
  __shared__ short sA[128 * 64];   // linear, swizzle handled via source+read
  __shared__ short sB[128 * 64];
  const int tid  = threadIdx.x;
  const int lane = tid & 63;
  const int wave = tid >> 6;
  const int wr = wave >> 1, wc = wave & 1;
  const int ln = lane & 15, g = lane >> 4;

  // XCD-aware bijective remap; grid is fixed (16, 64) => nwg = 1024, %8==0
  int flat = blockIdx.y * gridDim.x + blockIdx.x;
  int wg   = (flat & 7) * 128 + (flat >> 3);
  const int m0 = (wg >> 4) * 128, n0 = (wg & 15) * 128;

  const int lrow = lane >> 3;             // row within 8-row group (= row&7)
  const int lc4  = (lane & 7) ^ lrow;     // pre-swizzled global column slot

  f32x4 acc[4][4];
  #pragma unroll
  for (int i = 0; i < 4; i++)
    #pragma unroll
    for (int j = 0; j < 4; j++) acc[i][j] = {0.f, 0.f, 0.f, 0.f};

  for (int k0 = 0; k0 < K; k0 += 64) {
    #pragma unroll
    for (int i = 0; i < 4; i++) {
      int u = wave * 4 + i;               // 0..15, 8 rows each
      const short* ga = A  + (size_t)(m0 + u * 8 + lrow) * K + k0 + lc4 * 8;
      GLD16(ga, sA + u * 512);
      const short* gb = Bw + (size_t)(n0 + u * 8 + lrow) * K + k0 + lc4 * 8;
      GLD16(gb, sB + u * 512);
    }
    __syncthreads();

    #pragma unroll
    for (int kk = 0; kk < 64; kk += 32) {
      short8 af[4], bfr[4];
      #pragma unroll
      for (int m = 0; m < 4; m++) {
        int row  = wr * 64 + m * 16 + ln;
        int slot = ((kk >> 3) + g) ^ (ln & 7);
        af[m] = *(const short8*)(sA + row * 64 + slot * 8);
      }
      #pragma unroll
      for (int n = 0; n < 4; n++) {
        int row  = wc * 64 + n * 16 + ln;
        int slot = ((kk >> 3) + g) ^ (ln & 7);
        bfr[n] = *(const short8*)(sB + row * 64 + slot * 8);
      }
      #pragma unroll
      for (int m = 0; m < 4; m++)
        #pragma unroll
        for (int n = 0; n < 4; n++)
          acc[m][n] = __builtin_amdgcn_mfma_f32_16x16x32_bf16(af[m], bfr[n], acc[m][n], 0, 0, 0);
    }
    __syncthreads();
  }

  #pragma unroll
  for (int m = 0; m < 4; m++)
    #pragma unroll
    for (int n = 0; n < 4; n++)
      #pragma unroll
      for (int r = 0; r < 4; r++) {
        int row = m0 + wr * 64 + m * 16 + g * 4 + r;
        int col = n0 + wc * 64 + n * 16 + ln;
        float v = acc[m][n][r];
        if constexpr (OUT_F32) ((float*)Cp)[(size_t)row * N + col] = v;
        else                   ((short*)Cp)[(size_t)row * N + col] = f2bf(v);
      }
}

// ---------------------------------------------------------------------------
// RoPE apply, in place on bf16 Q (z=0, scaled by 1/sqrt(128)) and K (z=1).
// ---------------------------------------------------------------------------
__global__ __launch_bounds__(256)
void rope_apply(short* __restrict__ Qb, short* __restrict__ Kb,
                const float* __restrict__ cosT, const float* __restrict__ sinT)
{
  int idx = blockIdx.x * 256 + threadIdx.x;
  int z = blockIdx.y;
  short* ptr  = z ? Kb : Qb;
  float scale = z ? 1.0f : 0.08838834764831845f;
  int row = idx >> 7;
  int rem = idx & 127;
  int h = rem >> 3, ch = rem & 7;
  int l = row & (L_ - 1);
  short* base = ptr + (size_t)row * H_ + h * HD_ + ch * 8;
  short8 lo = *(short8*)base;
  short8 hi = *(short8*)(base + 64);
  const float* cp = cosT + l * 64 + ch * 8;
  const float* sp = sinT + l * 64 + ch * 8;
  short8 nlo, nhi;
  #pragma unroll
  for (int j = 0; j < 8; j++) {
    float c = cp[j], s = sp[j];
    float x0 = bf2f(lo[j]), x1 = bf2f(hi[j]);
    nlo[j] = f2bf((x0 * c - x1 * s) * scale);
    nhi[j] = f2bf((x1 * c + x0 * s) * scale);
  }
  *(short8*)base        = nlo;
  *(short8*)(base + 64) = nhi;
}

// ---------------------------------------------------------------------------
// V transpose: Vb [b,l,h*128+d]  ->  VT [bh][d][l]   (bf16, 64x64 LDS tiles,
// chunk-XOR swizzle: element (l,dd) at t[l*64 + (((dd>>3)^((l>>3)&7))<<3) +
// (dd&7)] -> b128 staging writes, conflict-free b16 gather reads.
// ---------------------------------------------------------------------------
__global__ __launch_bounds__(256)
void transpose_v(const short* __restrict__ Vb, short* __restrict__ VT)
{
  __shared__ short t[64 * 64];
  const int blk = blockIdx.x;           // 4096 = 64 bh x 32 ltile x 2 dtile
  const int dt = blk & 1, lt = (blk >> 1) & 31, bh = blk >> 6;
  const int b = bh >> 4, h = bh & 15;
  const int l0 = lt * 64, d0 = dt * 64;
  const int tid = threadIdx.x;
  #pragma unroll
  for (int i = 0; i < 2; i++) {
    int u = tid + i * 256;              // 512 chunks: r = l idx, c = d chunk
    int r = u >> 3, c = u & 7;
    short8 v = *(const short8*)(Vb + ((size_t)b * L_ + l0 + r) * H_ + h * HD_ + d0 + c * 8);
    *(short8*)&t[r * 64 + ((c ^ ((r >> 3) & 7)) << 3)] = v;
  }
  __syncthreads();
  #pragma unroll
  for (int i = 0; i < 2; i++) {
    int u = tid + i * 256;              // d = u>>3 (0..63), l chunk = u&7
    int d = u >> 3, lc = u & 7;
    short8 o;
    #pragma unroll
    for (int j = 0; j < 8; j++) {
      int l = lc * 8 + j;
      o[j] = t[l * 64 + (((d >> 3) ^ (lc & 7)) << 3) + (d & 7)];
    }
    *(short8*)(VT + ((size_t)bh * HD_ + d0 + d) * L_ + l0 + lc * 8) = o;
  }
}

// ---------------------------------------------------------------------------
// Flash attention (causal). Changes vs prev round:
//  - V pre-transposed globally -> staging is pure b128 (no scalar transpose).
//  - T14 async stage: tile t+1 global->reg issued before tile t compute;
//    LDS write after the post-PV barrier. 2 barriers/tile (mid one dropped:
//    lds_p is wave-private, lgkmcnt suffices).
//  - paired q-tiles (qt, 31-qt): 1024 blocks x constant 33 tiles.
//  - XCD-bijective remap: all 16 blocks of one (b,h) on one XCD.
//  - s_setprio(1) around MFMA clusters (T5).
// ---------------------------------------------------------------------------
__global__ __launch_bounds__(256)
void flash_attn(const short* __restrict__ Qb, const short* __restrict__ Kb,
                const short* __restrict__ VT, short* __restrict__ AO)
{
  __shared__ short lds_k[64][136];      // [kv][d], pad 8
  __shared__ short lds_vt[128][72];     // [d][kv], pad 8
  __shared__ short lds_p[4][16][72];    // per wave [qrow][kv^swz]

  const int flat = blockIdx.x;          // 1024
  const int xq = flat & 7;
  const int iq = flat >> 3;             // 0..127
  const int bh = xq + 8 * (iq >> 4);    // same-bh blocks share an XCD
  const int pair = iq & 15;
  const int h = bh & (NH_ - 1), b = bh >> 4;
  const int tid = threadIdx.x, wave = tid >> 6, lane = tid & 63;
  const int g = lane >> 4, ln = lane & 15;
  const size_t rowbase = (size_t)b * L_;
  const int colbase = h * HD_;
  const short* Kbh  = Kb + rowbase * H_ + colbase;        // row stride H_
  const short* VTbh = VT + (size_t)bh * HD_ * L_;         // row stride L_

  for (int ph = 0; ph < 2; ph++) {
    const int qt = ph ? (31 - pair) : pair;
    const int q0 = qt * 64;

    short8 aq[4];
    {
      const short* qp = Qb + (rowbase + q0 + wave * 16 + ln) * H_ + colbase + g * 8;
      #pragma unroll
      for (int c = 0; c < 4; c++) aq[c] = *(const short8*)(qp + c * 32);
    }
    f32x4 acc_o[8];
    #pragma unroll
    for (int i = 0; i < 8; i++) acc_o[i] = {0.f, 0.f, 0.f, 0.f};
    float mrow[4], lrow[4];
    #pragma unroll
    for (int r = 0; r < 4; r++) { mrow[r] = -__builtin_inff(); lrow[r] = 0.f; }

    // prologue: stage tile 0
    short8 kreg[4], vreg[4];
    #pragma unroll
    for (int i = 0; i < 4; i++) {
      int u = tid + i * 256;
      kreg[i] = *(const short8*)(Kbh + (size_t)(u >> 4) * H_ + (u & 15) * 8);
      vreg[i] = *(const short8*)(VTbh + (size_t)(u >> 3) * L_ + (u & 7) * 8);
    }
    __syncthreads();                    // prev phase's readers done
    #pragma unroll
    for (int i = 0; i < 4; i++) {
      int u = tid + i * 256;
      *(short8*)&lds_k[u >> 4][(u & 15) * 8] = kreg[i];
      *(short8*)&lds_vt[u >> 3][(u & 7) * 8] = vreg[i];
    }
    __syncthreads();

    for (int t = 0; t <= qt; ++t) {
      // issue next-tile loads early (hide HBM/L2 latency under compute)
      if (t < qt) {
        const int k0n = (t + 1) * 64;
        #pragma unroll
        for (int i = 0; i < 4; i++) {
          int u = tid + i * 256;
          kreg[i] = *(const short8*)(Kbh + (size_t)(k0n + (u >> 4)) * H_ + (u & 15) * 8);
          vreg[i] = *(const short8*)(VTbh + (size_t)(u >> 3) * L_ + k0n + (u & 7) * 8);
        }
      }
      // ---- S = Q K^T  (16 q rows x 64 kv) ----
      f32x4 sacc[4];
      __builtin_amdgcn_s_setprio(1);
      #pragma unroll
      for (int nsub = 0; nsub < 4; nsub++) {
        f32x4 a = {0.f, 0.f, 0.f, 0.f};
        #pragma unroll
        for (int c = 0; c < 4; c++) {
          short8 bk = *(const short8*)&lds_k[nsub * 16 + ln][c * 32 + g * 8];
          a = __builtin_amdgcn_mfma_f32_16x16x32_bf16(aq[c], bk, a, 0, 0, 0);
        }
        sacc[nsub] = a;
      }
      __builtin_amdgcn_s_setprio(0);
      // causal mask (only diagonal tile is partial)
      if (t == qt) {
        #pragma unroll
        for (int nsub = 0; nsub < 4; nsub++) {
          int kvloc = nsub * 16 + ln;
          #pragma unroll
          for (int r = 0; r < 4; r++) {
            int qloc = wave * 16 + g * 4 + r;
            if (kvloc > qloc) sacc[nsub][r] = -__builtin_inff();
          }
        }
      }
      // ---- online softmax ----
      f32x4 mx = sacc[0];
      #pragma unroll
      for (int nsub = 1; nsub < 4; nsub++)
        #pragma unroll
        for (int r = 0; r < 4; r++) mx[r] = fmaxf(mx[r], sacc[nsub][r]);
      #pragma unroll
      for (int r = 0; r < 4; r++) {
        float v = mx[r];
        v = fmaxf(v, __shfl_xor(v, 1));
        v = fmaxf(v, __shfl_xor(v, 2));
        v = fmaxf(v, __shfl_xor(v, 4));
        v = fmaxf(v, __shfl_xor(v, 8));
        mx[r] = v;
      }
      float f_[4];
      #pragma unroll
      for (int r = 0; r < 4; r++) {
        float mnew = fmaxf(mrow[r], mx[r]);
        f_[r] = __expf(mrow[r] - mnew);
        mrow[r] = mnew;
      }
      f32x4 psum = {0.f, 0.f, 0.f, 0.f};
      #pragma unroll
      for (int nsub = 0; nsub < 4; nsub++)
        #pragma unroll
        for (int r = 0; r < 4; r++) {
          float p = __expf(sacc[nsub][r] - mrow[r]);
          psum[r] += p;
          int q = g * 4 + r;
          lds_p[wave][q][(nsub * 16 + ln) ^ ((q & 8) << 1)] = f2bf(p);
        }
      #pragma unroll
      for (int r = 0; r < 4; r++) {
        float v = psum[r];
        v += __shfl_xor(v, 1);
        v += __shfl_xor(v, 2);
        v += __shfl_xor(v, 4);
        v += __shfl_xor(v, 8);
        lrow[r] = lrow[r] * f_[r] + v;
      }
      #pragma unroll
      for (int d = 0; d < 8; d++)
        #pragma unroll
        for (int r = 0; r < 4; r++) acc_o[d][r] *= f_[r];

      // ---- O += P V ----  (lds_p wave-private: no barrier needed)
      int pswz = (ln & 8) << 1;
      short8 pa0 = *(const short8*)&lds_p[wave][ln][(g * 8) ^ pswz];
      short8 pa1 = *(const short8*)&lds_p[wave][ln][(32 + g * 8) ^ pswz];
      __builtin_amdgcn_s_setprio(1);
      #pragma unroll
      for (int d = 0; d < 8; d++) {
        short8 vb0 = *(const short8*)&lds_vt[d * 16 + ln][g * 8];
        short8 vb1 = *(const short8*)&lds_vt[d * 16 + ln][32 + g * 8];
        acc_o[d] = __builtin_amdgcn_mfma_f32_16x16x32_bf16(pa0, vb0, acc_o[d], 0, 0, 0);
        acc_o[d] = __builtin_amdgcn_mfma_f32_16x16x32_bf16(pa1, vb1, acc_o[d], 0, 0, 0);
      }
      __builtin_amdgcn_s_setprio(0);
      __syncthreads();                  // all reads of lds_k/lds_vt done
      if (t < qt) {
        #pragma unroll
        for (int i = 0; i < 4; i++) {
          int u = tid + i * 256;
          *(short8*)&lds_k[u >> 4][(u & 15) * 8] = kreg[i];
          *(short8*)&lds_vt[u >> 3][(u & 7) * 8] = vreg[i];
        }
        __syncthreads();                // next tile visible
      }
    }

    // ---- write O ----
    #pragma unroll
    for (int r = 0; r < 4; r++) {
      float inv = 1.0f / lrow[r];
      int qrow = q0 + wave * 16 + g * 4 + r;
      short* op = AO + (rowbase + qrow) * H_ + colbase;
      #pragma unroll
      for (int d = 0; d < 8; d++)
        op[d * 16 + ln] = f2bf(acc_o[d][r] * inv);
    }
  }
}

// ---------------------------------------------------------------------------
extern "C" void kernel_launch(void* const* d_in, const int* in_sizes, int n_in,
                              void* d_out, int out_size, void* d_ws, size_t ws_size,
                              hipStream_t stream)
{
  const float* x  = (const float*)d_in[0];
  // d_in[1] = mask (tril causal) — implemented analytically
  const float* Wq = (const float*)d_in[2];
  const float* Wk = (const float*)d_in[3];
  const float* Wv = (const float*)d_in[4];
  const float* Wo = (const float*)d_in[5];
  float* out = (float*)d_out;

  char* ws = (char*)d_ws;
  const size_t SZ = (size_t)ML_ * H_ * sizeof(short);  // 32 MiB
  short* Qb = (short*)(ws);
  short* Kb = (short*)(ws + SZ);
  short* Vb = (short*)(ws + 2 * SZ);
  short* xb = (short*)(ws + 3 * SZ);   // x bf16; dead after V-GEMM
  short* VT = xb;                      // V^T [bh][d][l], reuses xb region
  short* AO = Vb;                      // attn out, reuses Vb (dead after transpose)
  short* Wb = (short*)(ws + 4 * SZ);   // 8 MiB, reused per weight
  float* cosT = (float*)(ws + 4 * SZ + (size_t)H_ * H_ * sizeof(short));
  float* sinT = cosT + (size_t)L_ * 64;

  rope_table<<<512, 256, 0, stream>>>(cosT, sinT);

  cvt_bf16<<<ML_ * H_ / 8 / 256, 256, 0, stream>>>(x, xb, ML_ * H_ / 8);

  dim3 gg(H_ / 128, ML_ / 128);   // (16, 64)
  cvt_bf16<<<H_ * H_ / 8 / 256, 256, 0, stream>>>(Wq, Wb, H_ * H_ / 8);
  gemm_bt_bf16<0><<<gg, 256, 0, stream>>>(xb, Wb, Qb, ML_, H_, H_);
  cvt_bf16<<<H_ * H_ / 8 / 256, 256, 0, stream>>>(Wk, Wb, H_ * H_ / 8);
  gemm_bt_bf16<0><<<gg, 256, 0, stream>>>(xb, Wb, Kb, ML_, H_, H_);
  cvt_bf16<<<H_ * H_ / 8 / 256, 256, 0, stream>>>(Wv, Wb, H_ * H_ / 8);
  gemm_bt_bf16<0><<<gg, 256, 0, stream>>>(xb, Wb, Vb, ML_, H_, H_);

  // x (xb) is dead now: transpose V into its slot
  transpose_v<<<64 * 32 * 2, 256, 0, stream>>>(Vb, VT);

  rope_apply<<<dim3(ML_ * NH_ * 8 / 256, 2), 256, 0, stream>>>(Qb, Kb, cosT, sinT);

  flash_attn<<<1024, 256, 0, stream>>>(Qb, Kb, VT, AO);

  cvt_bf16<<<H_ * H_ / 8 / 256, 256, 0, stream>>>(Wo, Wb, H_ * H_ / 8);
  gemm_bt_bf16<1><<<gg, 256, 0, stream>>>(AO, Wb, out, ML_, H_, H_);
}

// Round 4
// 537.130 us; speedup vs baseline: 2.9984x; 1.3315x over previous
//
#include <hip/hip_runtime.h>
#include <cstdint>
#include <cmath>

// Problem constants
#define B_   4
#define L_   2048
#define H_   2048
#define NH_  16
#define HD_  128
#define ML_  (B_*L_)   // 8192 rows total

using short8 = __attribute__((ext_vector_type(8))) short;
using f32x4  = __attribute__((ext_vector_type(4))) float;
using f32x16 = __attribute__((ext_vector_type(16))) float;
using uint4v = __attribute__((ext_vector_type(4))) unsigned;

__device__ inline short f2bf(float f){
  unsigned u = __builtin_bit_cast(unsigned, f);
  unsigned r = u + 0x7FFFu + ((u >> 16) & 1u);   // RNE
  return (short)(r >> 16);
}
__device__ inline float bf2f(short s){
  unsigned u = ((unsigned)(unsigned short)s) << 16;
  return __builtin_bit_cast(float, u);
}

// async global->LDS, 16B per lane, wave-uniform LDS base + lane*16
#define GLD16(gp, lp) __builtin_amdgcn_global_load_lds(                      \
    (const __attribute__((address_space(1))) void*)(gp),                     \
    (__attribute__((address_space(3))) void*)(lp), 16, 0, 0)

// pack 2 f32 -> 2 bf16 (RNE), dst.lo16 = lo, dst.hi16 = hi
__device__ inline unsigned cvtpk_bf16(float lo, float hi){
  unsigned d;
  asm("v_cvt_pk_bf16_f32 %0, %1, %2" : "=v"(d) : "v"(lo), "v"(hi));
  return d;
}
// after: a = [a_lo31, b_lo31], b = [a_hi31, b_hi31]
// NOTE: only safe when a and b are provably-distinct values (register
// allocator may coalesce equal-valued operands into one VGPR — that bug
// produced round-3's NaN in the cross-half reductions).
__device__ inline void permswap32(unsigned &a, unsigned &b){
  asm volatile("v_permlane32_swap_b32 %0, %1" : "+v"(a), "+v"(b));
}
// cross-half (lane ^ 32) reductions via shfl: immune to the coalescing issue
__device__ inline float cross_half_max(float x){
  return fmaxf(x, __shfl_xor(x, 32));
}
__device__ inline float cross_half_add(float x){
  return x + __shfl_xor(x, 32);
}

// ---------------------------------------------------------------------------
// RoPE cos/sin table: [2048][64] each, f32
// ---------------------------------------------------------------------------
__global__ void rope_table(float* __restrict__ cosT, float* __restrict__ sinT){
  int idx = blockIdx.x * 256 + threadIdx.x;
  if (idx >= L_ * 64) return;
  int l = idx >> 6, d = idx & 63;
  float invf = powf(10000.0f, -(float)d * (1.0f/64.0f));
  float fr = (float)l * invf;
  cosT[idx] = cosf(fr);
  sinT[idx] = sinf(fr);
}

// ---------------------------------------------------------------------------
// f32 -> bf16 elementwise (vectorized 8/thread)
// ---------------------------------------------------------------------------
__global__ __launch_bounds__(256)
void cvt_bf16(const float* __restrict__ in, short* __restrict__ out, int n8){
  int i = blockIdx.x * 256 + threadIdx.x;
  if (i >= n8) return;
  const float4* p = (const float4*)(in + (size_t)i * 8);
  float4 a = p[0], b = p[1];
  short8 s;
  s[0]=f2bf(a.x); s[1]=f2bf(a.y); s[2]=f2bf(a.z); s[3]=f2bf(a.w);
  s[4]=f2bf(b.x); s[5]=f2bf(b.y); s[6]=f2bf(b.z); s[7]=f2bf(b.w);
  *(short8*)(out + (size_t)i * 8) = s;
}

// ---------------------------------------------------------------------------
// GEMM: C[M,N] = A[M,K] @ B^T, A/B bf16, B is [N,K] row-major.
// 128x128 tile, BK=64, 256 threads (4 waves). m97 structure, unchanged.
// ---------------------------------------------------------------------------
template<int OUT_F32>
__global__ __launch_bounds__(256)
void gemm_bt_bf16(const short* __restrict__ A, const short* __restrict__ Bw,
                  void* __restrict__ Cp, int M, int N, int K)
{
  __shared__ short sA[128 * 64];
  __shared__ short sB[128 * 64];
  const int tid  = threadIdx.x;
  const int lane = tid & 63;
  const int wave = tid >> 6;
  const int wr = wave >> 1, wc = wave & 1;
  const int ln = lane & 15, g = lane >> 4;

  int flat = blockIdx.y * gridDim.x + blockIdx.x;
  int wg   = (flat & 7) * 128 + (flat >> 3);
  const int m0 = (wg >> 4) * 128, n0 = (wg & 15) * 128;

  const int lrow = lane >> 3;
  const int lc4  = (lane & 7) ^ lrow;

  f32x4 acc[4][4];
  #pragma unroll
  for (int i = 0; i < 4; i++)
    #pragma unroll
    for (int j = 0; j < 4; j++) acc[i][j] = {0.f, 0.f, 0.f, 0.f};

  for (int k0 = 0; k0 < K; k0 += 64) {
    #pragma unroll
    for (int i = 0; i < 4; i++) {
      int u = wave * 4 + i;
      const short* ga = A  + (size_t)(m0 + u * 8 + lrow) * K + k0 + lc4 * 8;
      GLD16(ga, sA + u * 512);
      const short* gb = Bw + (size_t)(n0 + u * 8 + lrow) * K + k0 + lc4 * 8;
      GLD16(gb, sB + u * 512);
    }
    __syncthreads();

    #pragma unroll
    for (int kk = 0; kk < 64; kk += 32) {
      short8 af[4], bfr[4];
      #pragma unroll
      for (int m = 0; m < 4; m++) {
        int row  = wr * 64 + m * 16 + ln;
        int slot = ((kk >> 3) + g) ^ (ln & 7);
        af[m] = *(const short8*)(sA + row * 64 + slot * 8);
      }
      #pragma unroll
      for (int n = 0; n < 4; n++) {
        int row  = wc * 64 + n * 16 + ln;
        int slot = ((kk >> 3) + g) ^ (ln & 7);
        bfr[n] = *(const short8*)(sB + row * 64 + slot * 8);
      }
      #pragma unroll
      for (int m = 0; m < 4; m++)
        #pragma unroll
        for (int n = 0; n < 4; n++)
          acc[m][n] = __builtin_amdgcn_mfma_f32_16x16x32_bf16(af[m], bfr[n], acc[m][n], 0, 0, 0);
    }
    __syncthreads();
  }

  #pragma unroll
  for (int m = 0; m < 4; m++)
    #pragma unroll
    for (int n = 0; n < 4; n++)
      #pragma unroll
      for (int r = 0; r < 4; r++) {
        int row = m0 + wr * 64 + m * 16 + g * 4 + r;
        int col = n0 + wc * 64 + n * 16 + ln;
        float v = acc[m][n][r];
        if constexpr (OUT_F32) ((float*)Cp)[(size_t)row * N + col] = v;
        else                   ((short*)Cp)[(size_t)row * N + col] = f2bf(v);
      }
}

// ---------------------------------------------------------------------------
// RoPE apply, in place on bf16 Q (z=0, scaled by 1/sqrt(128)) and K (z=1).
// ---------------------------------------------------------------------------
__global__ __launch_bounds__(256)
void rope_apply(short* __restrict__ Qb, short* __restrict__ Kb,
                const float* __restrict__ cosT, const float* __restrict__ sinT)
{
  int idx = blockIdx.x * 256 + threadIdx.x;
  int z = blockIdx.y;
  short* ptr  = z ? Kb : Qb;
  float scale = z ? 1.0f : 0.08838834764831845f;
  int row = idx >> 7;
  int rem = idx & 127;
  int h = rem >> 3, ch = rem & 7;
  int l = row & (L_ - 1);
  short* base = ptr + (size_t)row * H_ + h * HD_ + ch * 8;
  short8 lo = *(short8*)base;
  short8 hi = *(short8*)(base + 64);
  const float* cp = cosT + l * 64 + ch * 8;
  const float* sp = sinT + l * 64 + ch * 8;
  short8 nlo, nhi;
  #pragma unroll
  for (int j = 0; j < 8; j++) {
    float c = cp[j], s = sp[j];
    float x0 = bf2f(lo[j]), x1 = bf2f(hi[j]);
    nlo[j] = f2bf((x0 * c - x1 * s) * scale);
    nhi[j] = f2bf((x1 * c + x0 * s) * scale);
  }
  *(short8*)base        = nlo;
  *(short8*)(base + 64) = nhi;
}

// ---------------------------------------------------------------------------
// V transpose: Vb [b,l,h*128+d]  ->  VT [bh][d][l]   (unchanged)
// ---------------------------------------------------------------------------
__global__ __launch_bounds__(256)
void transpose_v(const short* __restrict__ Vb, short* __restrict__ VT)
{
  __shared__ short t[64 * 64];
  const int blk = blockIdx.x;           // 4096 = 64 bh x 32 ltile x 2 dtile
  const int dt = blk & 1, lt = (blk >> 1) & 31, bh = blk >> 6;
  const int b = bh >> 4, h = bh & 15;
  const int l0 = lt * 64, d0 = dt * 64;
  const int tid = threadIdx.x;
  #pragma unroll
  for (int i = 0; i < 2; i++) {
    int u = tid + i * 256;
    int r = u >> 3, c = u & 7;
    short8 v = *(const short8*)(Vb + ((size_t)b * L_ + l0 + r) * H_ + h * HD_ + d0 + c * 8);
    *(short8*)&t[r * 64 + ((c ^ ((r >> 3) & 7)) << 3)] = v;
  }
  __syncthreads();
  #pragma unroll
  for (int i = 0; i < 2; i++) {
    int u = tid + i * 256;
    int d = u >> 3, lc = u & 7;
    short8 o;
    #pragma unroll
    for (int j = 0; j < 8; j++) {
      int l = lc * 8 + j;
      o[j] = t[l * 64 + (((d >> 3) ^ (lc & 7)) << 3) + (d & 7)];
    }
    *(short8*)(VT + ((size_t)bh * HD_ + d0 + d) * L_ + l0 + lc * 8) = o;
  }
}

// ---------------------------------------------------------------------------
// Flash attention, 8-wave 32x32 swapped-QK^T structure (m214 port):
//  - block = 8 waves (512 thr), QBLK=256 (32 q rows / wave), KVBLK=64.
//  - S^T = mfma_32x32x16(K, Q): lane pair (l31, l31+32) owns the full P-row
//    of q = q0+wave*32+l31 (kv at reg r: (r&3)+8*(r>>2)+4*hi + 32*kb).
//    Softmax in-register: in-lane fmax/add + __shfl_xor(.,32) cross-half.
//  - P->bf16 A-frags via v_cvt_pk_bf16_f32 + permlane32_swap (T12 recipe;
//    operands there are distinct values -> no register-coalescing hazard).
//  - K [64][128] and V^T [128][64] double-buffered in LDS via global_load_lds
//    w=16, chunk-XOR swizzle (chunk ^= row&7) applied on the global source and
//    the ds_read side (rule #21).
//  - 1 barrier/tile; per-q rescale factors broadcast via per-wave f_lds.
// ---------------------------------------------------------------------------
__global__ __launch_bounds__(512, 2)
void flash_attn(const short* __restrict__ Qb, const short* __restrict__ Kb,
                const short* __restrict__ VT, short* __restrict__ AO)
{
  __shared__ short lds_k[2][64 * 128];    // [kv][d-chunks swz]  32 KiB
  __shared__ short lds_v[2][128 * 64];    // [d][kv-chunks swz]  32 KiB
  __shared__ float f_lds[8][32];

  const int blk = blockIdx.x;             // 512 = 64 bh x 8 q-blocks
  int bh, j;
  if (blk < 256) { bh = blk & 63; j = 7 - (blk >> 6); }        // heavy first
  else           { int u = blk - 256; bh = u & 63; j = 3 - (u >> 6); } // light last
  const int q0 = j * 256;
  const int T  = 4 * j + 4;               // kv tiles for this q-block
  const int h = bh & 15, b = bh >> 4;
  const int tid = threadIdx.x, wave = tid >> 6, lane = tid & 63;
  const int hi = lane >> 5, l31 = lane & 31;
  const size_t rowbase = (size_t)b * L_;
  const int colbase = h * HD_;
  const short* Kbh  = Kb + rowbase * H_ + colbase;     // row stride H_
  const short* VTbh = VT + (size_t)bh * HD_ * L_;      // row stride L_
  const int qw = q0 + wave * 32;
  const int qabs = qw + l31;

  // Q fragments (B-operand): qf[c][j] = Q[qabs][c*16 + hi*8 + j]
  short8 qf[8];
  {
    const short* qp = Qb + (rowbase + qabs) * H_ + colbase + hi * 8;
    #pragma unroll
    for (int c = 0; c < 8; c++) qf[c] = *(const short8*)(qp + c * 16);
  }

  f32x16 acc_o[4];
  #pragma unroll
  for (int d = 0; d < 4; d++)
    #pragma unroll
    for (int r = 0; r < 16; r++) acc_o[d][r] = 0.f;
  float m_ = -__builtin_inff(), l_ = 0.f;

  // stage one KV tile into buffer bufi (all 8 waves cooperate)
  auto stage = [&](int k0s, int bufi) {
    #pragma unroll
    for (int i = 0; i < 2; i++) {
      int c = wave * 2 + i;               // 0..15, wave-uniform
      {
        int grow = k0s + c * 4 + (lane >> 4);          // kv row
        const short* gp = Kbh + (size_t)grow * H_ + (((lane & 15) ^ (grow & 7)) * 8);
        GLD16(gp, &lds_k[bufi][c * 512]);
      }
      {
        int d = c * 8 + (lane >> 3);                   // head-dim row
        const short* gp = VTbh + (size_t)d * L_ + k0s + (((lane & 7) ^ (d & 7)) * 8);
        GLD16(gp, &lds_v[bufi][c * 512]);
      }
    }
  };

  stage(0, 0);
  __syncthreads();                        // vmcnt(0) drained: buf0 ready

  for (int t = 0; t < T; ++t) {
    const int k0 = t * 64;
    if (t + 1 < T) stage((t + 1) * 64, (t + 1) & 1);
    const short* kb_ = lds_k[t & 1];
    const short* vb_ = lds_v[t & 1];

    if (k0 <= qw + 31) {                  // wave-uniform active check
      // ---- S^T = K Q^T : 2 x (8-chain) 32x32x16 MFMA ----
      f32x16 p0, p1;
      #pragma unroll
      for (int r = 0; r < 16; r++) { p0[r] = 0.f; p1[r] = 0.f; }
      __builtin_amdgcn_s_setprio(1);
      #pragma unroll
      for (int c = 0; c < 8; c++) {
        int ch = (c * 2 + hi) ^ (l31 & 7);
        short8 kf0 = *(const short8*)(kb_ + l31 * 128 + ch * 8);
        short8 kf1 = *(const short8*)(kb_ + (32 + l31) * 128 + ch * 8);
        p0 = __builtin_amdgcn_mfma_f32_32x32x16_bf16(kf0, qf[c], p0, 0, 0, 0);
        p1 = __builtin_amdgcn_mfma_f32_32x32x16_bf16(kf1, qf[c], p1, 0, 0, 0);
      }
      __builtin_amdgcn_s_setprio(0);

      // ---- causal mask (<=2 tiles per wave hit this) ----
      if (k0 + 63 > qw) {
        #pragma unroll
        for (int r = 0; r < 16; r++) {
          int kvl = (r & 3) + 8 * (r >> 2) + 4 * hi;
          if (k0 + kvl > qabs)      p0[r] = -__builtin_inff();
          if (k0 + 32 + kvl > qabs) p1[r] = -__builtin_inff();
        }
      }

      // ---- online softmax, fully in-register ----
      float mt = p0[0];
      #pragma unroll
      for (int r = 1; r < 16; r++) mt = fmaxf(mt, p0[r]);
      #pragma unroll
      for (int r = 0; r < 16; r++) mt = fmaxf(mt, p1[r]);
      mt = cross_half_max(mt);
      float mnew = fmaxf(m_, mt);
      float f = __expf(m_ - mnew);
      m_ = mnew;
      float ls = 0.f;
      #pragma unroll
      for (int r = 0; r < 16; r++) { p0[r] = __expf(p0[r] - mnew); ls += p0[r]; }
      #pragma unroll
      for (int r = 0; r < 16; r++) { p1[r] = __expf(p1[r] - mnew); ls += p1[r]; }
      ls = cross_half_add(ls);
      l_ = l_ * f + ls;

      // ---- broadcast per-q rescale factor, rescale O ----
      if (lane < 32) f_lds[wave][lane] = f;
      f32x4 fr[4];
      #pragma unroll
      for (int i = 0; i < 4; i++)
        fr[i] = *(const f32x4*)&f_lds[wave][i * 8 + hi * 4];
      #pragma unroll
      for (int d = 0; d < 4; d++)
        #pragma unroll
        for (int r = 0; r < 16; r++) acc_o[d][r] *= fr[r >> 2][r & 3];

      // ---- O += P V : build A-frags (cvt_pk + permlane32_swap), 16 MFMA ----
      __builtin_amdgcn_s_setprio(1);
      #pragma unroll
      for (int ks = 0; ks < 4; ks++) {
        const f32x16 &pp = (ks < 2) ? p0 : p1;
        const int kk = (ks & 1) * 8;
        unsigned a0 = cvtpk_bf16(pp[kk + 0], pp[kk + 1]);
        unsigned b0 = cvtpk_bf16(pp[kk + 4], pp[kk + 5]);
        permswap32(a0, b0);               // a0 = word0, b0 = word2
        unsigned a1 = cvtpk_bf16(pp[kk + 2], pp[kk + 3]);
        unsigned b1 = cvtpk_bf16(pp[kk + 6], pp[kk + 7]);
        permswap32(a1, b1);               // a1 = word1, b1 = word3
        uint4v w; w[0] = a0; w[1] = a1; w[2] = b0; w[3] = b1;
        short8 af = __builtin_bit_cast(short8, w);
        #pragma unroll
        for (int db = 0; db < 4; db++) {
          int d  = db * 32 + l31;
          int ch = (ks * 2 + hi) ^ (d & 7);
          short8 vf = *(const short8*)(vb_ + d * 64 + ch * 8);
          acc_o[db] = __builtin_amdgcn_mfma_f32_32x32x16_bf16(af, vf, acc_o[db], 0, 0, 0);
        }
      }
      __builtin_amdgcn_s_setprio(0);
    }
    __syncthreads();   // readers done with buf[t&1]; stage(t+1) landed
  }

  // ---- normalize and write O ----
  if (lane < 32) f_lds[wave][lane] = 1.0f / l_;
  f32x4 lr[4];
  #pragma unroll
  for (int i = 0; i < 4; i++)
    lr[i] = *(const f32x4*)&f_lds[wave][i * 8 + hi * 4];
  #pragma unroll
  for (int db = 0; db < 4; db++)
    #pragma unroll
    for (int r = 0; r < 16; r++) {
      int row = qw + (r & 3) + 8 * (r >> 2) + 4 * hi;
      AO[(rowbase + row) * H_ + colbase + db * 32 + l31] =
          f2bf(acc_o[db][r] * lr[r >> 2][r & 3]);
    }
}

// ---------------------------------------------------------------------------
extern "C" void kernel_launch(void* const* d_in, const int* in_sizes, int n_in,
                              void* d_out, int out_size, void* d_ws, size_t ws_size,
                              hipStream_t stream)
{
  const float* x  = (const float*)d_in[0];
  // d_in[1] = mask (tril causal) — implemented analytically
  const float* Wq = (const float*)d_in[2];
  const float* Wk = (const float*)d_in[3];
  const float* Wv = (const float*)d_in[4];
  const float* Wo = (const float*)d_in[5];
  float* out = (float*)d_out;

  char* ws = (char*)d_ws;
  const size_t SZ = (size_t)ML_ * H_ * sizeof(short);  // 32 MiB
  short* Qb = (short*)(ws);
  short* Kb = (short*)(ws + SZ);
  short* Vb = (short*)(ws + 2 * SZ);
  short* xb = (short*)(ws + 3 * SZ);   // x bf16; dead after V-GEMM
  short* VT = xb;                      // V^T [bh][d][l], reuses xb region
  short* AO = Vb;                      // attn out, reuses Vb (dead after transpose)
  short* Wb = (short*)(ws + 4 * SZ);   // 8 MiB, reused per weight
  float* cosT = (float*)(ws + 4 * SZ + (size_t)H_ * H_ * sizeof(short));
  float* sinT = cosT + (size_t)L_ * 64;

  rope_table<<<512, 256, 0, stream>>>(cosT, sinT);

  cvt_bf16<<<ML_ * H_ / 8 / 256, 256, 0, stream>>>(x, xb, ML_ * H_ / 8);

  dim3 gg(H_ / 128, ML_ / 128);   // (16, 64)
  cvt_bf16<<<H_ * H_ / 8 / 256, 256, 0, stream>>>(Wq, Wb, H_ * H_ / 8);
  gemm_bt_bf16<0><<<gg, 256, 0, stream>>>(xb, Wb, Qb, ML_, H_, H_);
  cvt_bf16<<<H_ * H_ / 8 / 256, 256, 0, stream>>>(Wk, Wb, H_ * H_ / 8);
  gemm_bt_bf16<0><<<gg, 256, 0, stream>>>(xb, Wb, Kb, ML_, H_, H_);
  cvt_bf16<<<H_ * H_ / 8 / 256, 256, 0, stream>>>(Wv, Wb, H_ * H_ / 8);
  gemm_bt_bf16<0><<<gg, 256, 0, stream>>>(xb, Wb, Vb, ML_, H_, H_);

  // x (xb) is dead now: transpose V into its slot
  transpose_v<<<64 * 32 * 2, 256, 0, stream>>>(Vb, VT);

  rope_apply<<<dim3(ML_ * NH_ * 8 / 256, 2), 256, 0, stream>>>(Qb, Kb, cosT, sinT);

  flash_attn<<<512, 512, 0, stream>>>(Qb, Kb, VT, AO);

  cvt_bf16<<<H_ * H_ / 8 / 256, 256, 0, stream>>>(Wo, Wb, H_ * H_ / 8);
  gemm_bt_bf16<1><<<gg, 256, 0, stream>>>(AO, Wb, out, ML_, H_, H_);
}

// Round 5
// 462.132 us; speedup vs baseline: 3.4850x; 1.1623x over previous
//
#include <hip/hip_runtime.h>
#include <cstdint>
#include <cmath>

// Problem constants
#define B_   4
#define L_   2048
#define H_   2048
#define NH_  16
#define HD_  128
#define ML_  (B_*L_)   // 8192 rows total

using short8 = __attribute__((ext_vector_type(8))) short;
using f32x4  = __attribute__((ext_vector_type(4))) float;
using f32x16 = __attribute__((ext_vector_type(16))) float;
using uint4v = __attribute__((ext_vector_type(4))) unsigned;

__device__ inline short f2bf(float f){
  unsigned u = __builtin_bit_cast(unsigned, f);
  unsigned r = u + 0x7FFFu + ((u >> 16) & 1u);   // RNE
  return (short)(r >> 16);
}
__device__ inline float bf2f(short s){
  unsigned u = ((unsigned)(unsigned short)s) << 16;
  return __builtin_bit_cast(float, u);
}

// async global->LDS, 16B per lane, wave-uniform LDS base + lane*16
#define GLD16(gp, lp) __builtin_amdgcn_global_load_lds(                      \
    (const __attribute__((address_space(1))) void*)(gp),                     \
    (__attribute__((address_space(3))) void*)(lp), 16, 0, 0)

// pack 2 f32 -> 2 bf16 (RNE), dst.lo16 = lo, dst.hi16 = hi
__device__ inline unsigned cvtpk_bf16(float lo, float hi){
  unsigned d;
  asm("v_cvt_pk_bf16_f32 %0, %1, %2" : "=v"(d) : "v"(lo), "v"(hi));
  return d;
}
// NOTE: only safe when a and b are provably-distinct values (round-3 NaN:
// equal-valued operands can be register-coalesced into one VGPR).
__device__ inline void permswap32(unsigned &a, unsigned &b){
  asm volatile("v_permlane32_swap_b32 %0, %1" : "+v"(a), "+v"(b));
}
__device__ inline float cross_half_max(float x){
  return fmaxf(x, __shfl_xor(x, 32));
}
__device__ inline float cross_half_add(float x){
  return x + __shfl_xor(x, 32);
}

// ---------------------------------------------------------------------------
// RoPE cos/sin table: [2048][64] each, f32
// ---------------------------------------------------------------------------
__global__ void rope_table(float* __restrict__ cosT, float* __restrict__ sinT){
  int idx = blockIdx.x * 256 + threadIdx.x;
  if (idx >= L_ * 64) return;
  int l = idx >> 6, d = idx & 63;
  float invf = powf(10000.0f, -(float)d * (1.0f/64.0f));
  float fr = (float)l * invf;
  cosT[idx] = cosf(fr);
  sinT[idx] = sinf(fr);
}

// ---------------------------------------------------------------------------
// f32 -> bf16 elementwise (vectorized 8/thread)
// ---------------------------------------------------------------------------
__global__ __launch_bounds__(256)
void cvt_bf16(const float* __restrict__ in, short* __restrict__ out, int n8){
  int i = blockIdx.x * 256 + threadIdx.x;
  if (i >= n8) return;
  const float4* p = (const float4*)(in + (size_t)i * 8);
  float4 a = p[0], b = p[1];
  short8 s;
  s[0]=f2bf(a.x); s[1]=f2bf(a.y); s[2]=f2bf(a.z); s[3]=f2bf(a.w);
  s[4]=f2bf(b.x); s[5]=f2bf(b.y); s[6]=f2bf(b.z); s[7]=f2bf(b.w);
  *(short8*)(out + (size_t)i * 8) = s;
}

// ---------------------------------------------------------------------------
// GEMM 256x256 tile, counted-vmcnt deep pipeline (T3+T4):
//   C[8192,2048] = A[8192,2048] @ B^T   (A,B bf16; B = [N,K] row-major)
//   BK=32, 4 LDS buffers (128 KiB), 8 waves (2M x 4N), per-wave out 128x64.
//   Per tile t: vmcnt(8) [stages t+1,t+2 stay in flight -> pipe never
//   drains] -> s_barrier -> 12 x ds_read_b128 -> issue stage(t+3) -> 32 MFMA.
//   Race-free with ONE barrier/tile: stage(t+3) overwrites buf[(t-1)&3];
//   every wave's tile-(t-1) ds_reads are consumed by its MFMAs BEFORE it
//   reaches tile t's barrier, and stage(t+3) is issued after that barrier.
//   LDS swizzle: slot = chunk ^ (row&3) on global source AND read (rule #21).
// ---------------------------------------------------------------------------
template<int OUT_F32>
__global__ __launch_bounds__(512, 2)
void gemm256_bt(const short* __restrict__ A, const short* __restrict__ Bw,
                void* __restrict__ Cp)
{
  constexpr int K = 2048, N = 2048;
  __shared__ short sA[4][256 * 32];      // 64 KiB
  __shared__ short sB[4][256 * 32];      // 64 KiB
  const int tid  = threadIdx.x;
  const int lane = tid & 63;
  const int wave = tid >> 6;
  const int wr = wave >> 2, wc = wave & 3;   // 2M x 4N wave grid
  const int ln = lane & 15, g = lane >> 4;

  // 256 blocks: n-tile = blk&7 (one per XCD -> shared B panel in L2),
  // m-tile = blk>>3
  const int blk = blockIdx.x;
  const int m0 = (blk >> 3) * 256, n0 = (blk & 7) * 256;

  // staging geometry: 1024 16B-slots per (matrix, tile); 2 per thread
  const int u0 = wave * 64 + lane;           // 0..511   -> rows 0..127
  const int u1 = u0 + 512;                   // 512..1023-> rows 128..255
  const int r0 = u0 >> 2, c0 = ((u0 & 3) ^ (r0 & 3)) * 8;
  const int r1 = u1 >> 2, c1 = ((u1 & 3) ^ (r1 & 3)) * 8;

  f32x4 acc[8][4];
  #pragma unroll
  for (int m = 0; m < 8; m++)
    #pragma unroll
    for (int n = 0; n < 4; n++) acc[m][n] = {0.f, 0.f, 0.f, 0.f};

#define STAGE256(T) do {                                                     \
    const int _b = (T) & 3; const int _k = (T) * 32;                         \
    GLD16(A  + (size_t)(m0 + r0) * K + _k + c0, &sA[_b][wave * 512]);        \
    GLD16(A  + (size_t)(m0 + r1) * K + _k + c1, &sA[_b][4096 + wave * 512]); \
    GLD16(Bw + (size_t)(n0 + r0) * K + _k + c0, &sB[_b][wave * 512]);        \
    GLD16(Bw + (size_t)(n0 + r1) * K + _k + c1, &sB[_b][4096 + wave * 512]); \
  } while (0)

#define TILE256(T, VMN, PF) do {                                             \
    asm volatile("s_waitcnt vmcnt(" #VMN ")" ::: "memory");                  \
    __builtin_amdgcn_s_barrier();                                            \
    asm volatile("" ::: "memory");                                           \
    const short* _at = &sA[(T) & 3][0];                                      \
    const short* _bt = &sB[(T) & 3][0];                                      \
    short8 af[8], bfr[4];                                                    \
    const int _sl = (g ^ (ln & 3)) * 8;                                      \
    _Pragma("unroll")                                                        \
    for (int m = 0; m < 8; m++)                                              \
      af[m] = *(const short8*)(_at + (wr * 128 + m * 16 + ln) * 32 + _sl);   \
    _Pragma("unroll")                                                        \
    for (int n = 0; n < 4; n++)                                              \
      bfr[n] = *(const short8*)(_bt + (wc * 64 + n * 16 + ln) * 32 + _sl);   \
    if (PF) STAGE256((T) + 3);                                               \
    __builtin_amdgcn_s_setprio(1);                                           \
    _Pragma("unroll")                                                        \
    for (int m = 0; m < 8; m++)                                              \
      _Pragma("unroll")                                                      \
      for (int n = 0; n < 4; n++)                                            \
        acc[m][n] = __builtin_amdgcn_mfma_f32_16x16x32_bf16(af[m], bfr[n],   \
                                                            acc[m][n], 0, 0, 0); \
    __builtin_amdgcn_s_setprio(0);                                           \
  } while (0)

  // prologue: 3 tiles in flight
  STAGE256(0); STAGE256(1); STAGE256(2);

  for (int t = 0; t < 61; ++t) TILE256(t, 8, true);   // prefetch t+3 = 3..63
  TILE256(61, 8, false);
  TILE256(62, 4, false);
  TILE256(63, 0, false);

#undef STAGE256
#undef TILE256

  // epilogue: C/D layout col=lane&15, row=(lane>>4)*4+reg
  #pragma unroll
  for (int m = 0; m < 8; m++)
    #pragma unroll
    for (int n = 0; n < 4; n++)
      #pragma unroll
      for (int r = 0; r < 4; r++) {
        int row = m0 + wr * 128 + m * 16 + g * 4 + r;
        int col = n0 + wc * 64 + n * 16 + ln;
        float v = acc[m][n][r];
        if constexpr (OUT_F32) ((float*)Cp)[(size_t)row * N + col] = v;
        else                   ((short*)Cp)[(size_t)row * N + col] = f2bf(v);
      }
}

// ---------------------------------------------------------------------------
// RoPE apply, in place on bf16 Q (z=0, scaled by 1/sqrt(128)) and K (z=1).
// ---------------------------------------------------------------------------
__global__ __launch_bounds__(256)
void rope_apply(short* __restrict__ Qb, short* __restrict__ Kb,
                const float* __restrict__ cosT, const float* __restrict__ sinT)
{
  int idx = blockIdx.x * 256 + threadIdx.x;
  int z = blockIdx.y;
  short* ptr  = z ? Kb : Qb;
  float scale = z ? 1.0f : 0.08838834764831845f;
  int row = idx >> 7;
  int rem = idx & 127;
  int h = rem >> 3, ch = rem & 7;
  int l = row & (L_ - 1);
  short* base = ptr + (size_t)row * H_ + h * HD_ + ch * 8;
  short8 lo = *(short8*)base;
  short8 hi = *(short8*)(base + 64);
  const float* cp = cosT + l * 64 + ch * 8;
  const float* sp = sinT + l * 64 + ch * 8;
  short8 nlo, nhi;
  #pragma unroll
  for (int j = 0; j < 8; j++) {
    float c = cp[j], s = sp[j];
    float x0 = bf2f(lo[j]), x1 = bf2f(hi[j]);
    nlo[j] = f2bf((x0 * c - x1 * s) * scale);
    nhi[j] = f2bf((x1 * c + x0 * s) * scale);
  }
  *(short8*)base        = nlo;
  *(short8*)(base + 64) = nhi;
}

// ---------------------------------------------------------------------------
// V transpose: Vb [b,l,h*128+d]  ->  VT [bh][d][l]   (unchanged)
// ---------------------------------------------------------------------------
__global__ __launch_bounds__(256)
void transpose_v(const short* __restrict__ Vb, short* __restrict__ VT)
{
  __shared__ short t[64 * 64];
  const int blk = blockIdx.x;           // 4096 = 64 bh x 32 ltile x 2 dtile
  const int dt = blk & 1, lt = (blk >> 1) & 31, bh = blk >> 6;
  const int b = bh >> 4, h = bh & 15;
  const int l0 = lt * 64, d0 = dt * 64;
  const int tid = threadIdx.x;
  #pragma unroll
  for (int i = 0; i < 2; i++) {
    int u = tid + i * 256;
    int r = u >> 3, c = u & 7;
    short8 v = *(const short8*)(Vb + ((size_t)b * L_ + l0 + r) * H_ + h * HD_ + d0 + c * 8);
    *(short8*)&t[r * 64 + ((c ^ ((r >> 3) & 7)) << 3)] = v;
  }
  __syncthreads();
  #pragma unroll
  for (int i = 0; i < 2; i++) {
    int u = tid + i * 256;
    int d = u >> 3, lc = u & 7;
    short8 o;
    #pragma unroll
    for (int j = 0; j < 8; j++) {
      int l = lc * 8 + j;
      o[j] = t[l * 64 + (((d >> 3) ^ (lc & 7)) << 3) + (d & 7)];
    }
    *(short8*)(VT + ((size_t)bh * HD_ + d0 + d) * L_ + l0 + lc * 8) = o;
  }
}

// ---------------------------------------------------------------------------
// Flash attention, 8-wave 32x32 swapped-QK^T structure (unchanged from R4)
// ---------------------------------------------------------------------------
__global__ __launch_bounds__(512, 2)
void flash_attn(const short* __restrict__ Qb, const short* __restrict__ Kb,
                const short* __restrict__ VT, short* __restrict__ AO)
{
  __shared__ short lds_k[2][64 * 128];    // [kv][d-chunks swz]  32 KiB
  __shared__ short lds_v[2][128 * 64];    // [d][kv-chunks swz]  32 KiB
  __shared__ float f_lds[8][32];

  const int blk = blockIdx.x;             // 512 = 64 bh x 8 q-blocks
  int bh, j;
  if (blk < 256) { bh = blk & 63; j = 7 - (blk >> 6); }        // heavy first
  else           { int u = blk - 256; bh = u & 63; j = 3 - (u >> 6); } // light last
  const int q0 = j * 256;
  const int T  = 4 * j + 4;               // kv tiles for this q-block
  const int h = bh & 15, b = bh >> 4;
  const int tid = threadIdx.x, wave = tid >> 6, lane = tid & 63;
  const int hi = lane >> 5, l31 = lane & 31;
  const size_t rowbase = (size_t)b * L_;
  const int colbase = h * HD_;
  const short* Kbh  = Kb + rowbase * H_ + colbase;     // row stride H_
  const short* VTbh = VT + (size_t)bh * HD_ * L_;      // row stride L_
  const int qw = q0 + wave * 32;
  const int qabs = qw + l31;

  // Q fragments (B-operand): qf[c][j] = Q[qabs][c*16 + hi*8 + j]
  short8 qf[8];
  {
    const short* qp = Qb + (rowbase + qabs) * H_ + colbase + hi * 8;
    #pragma unroll
    for (int c = 0; c < 8; c++) qf[c] = *(const short8*)(qp + c * 16);
  }

  f32x16 acc_o[4];
  #pragma unroll
  for (int d = 0; d < 4; d++)
    #pragma unroll
    for (int r = 0; r < 16; r++) acc_o[d][r] = 0.f;
  float m_ = -__builtin_inff(), l_ = 0.f;

  // stage one KV tile into buffer bufi (all 8 waves cooperate)
  auto stage = [&](int k0s, int bufi) {
    #pragma unroll
    for (int i = 0; i < 2; i++) {
      int c = wave * 2 + i;               // 0..15, wave-uniform
      {
        int grow = k0s + c * 4 + (lane >> 4);          // kv row
        const short* gp = Kbh + (size_t)grow * H_ + (((lane & 15) ^ (grow & 7)) * 8);
        GLD16(gp, &lds_k[bufi][c * 512]);
      }
      {
        int d = c * 8 + (lane >> 3);                   // head-dim row
        const short* gp = VTbh + (size_t)d * L_ + k0s + (((lane & 7) ^ (d & 7)) * 8);
        GLD16(gp, &lds_v[bufi][c * 512]);
      }
    }
  };

  stage(0, 0);
  __syncthreads();                        // vmcnt(0) drained: buf0 ready

  for (int t = 0; t < T; ++t) {
    const int k0 = t * 64;
    if (t + 1 < T) stage((t + 1) * 64, (t + 1) & 1);
    const short* kb_ = lds_k[t & 1];
    const short* vb_ = lds_v[t & 1];

    if (k0 <= qw + 31) {                  // wave-uniform active check
      // ---- S^T = K Q^T : 2 x (8-chain) 32x32x16 MFMA ----
      f32x16 p0, p1;
      #pragma unroll
      for (int r = 0; r < 16; r++) { p0[r] = 0.f; p1[r] = 0.f; }
      __builtin_amdgcn_s_setprio(1);
      #pragma unroll
      for (int c = 0; c < 8; c++) {
        int ch = (c * 2 + hi) ^ (l31 & 7);
        short8 kf0 = *(const short8*)(kb_ + l31 * 128 + ch * 8);
        short8 kf1 = *(const short8*)(kb_ + (32 + l31) * 128 + ch * 8);
        p0 = __builtin_amdgcn_mfma_f32_32x32x16_bf16(kf0, qf[c], p0, 0, 0, 0);
        p1 = __builtin_amdgcn_mfma_f32_32x32x16_bf16(kf1, qf[c], p1, 0, 0, 0);
      }
      __builtin_amdgcn_s_setprio(0);

      // ---- causal mask (<=2 tiles per wave hit this) ----
      if (k0 + 63 > qw) {
        #pragma unroll
        for (int r = 0; r < 16; r++) {
          int kvl = (r & 3) + 8 * (r >> 2) + 4 * hi;
          if (k0 + kvl > qabs)      p0[r] = -__builtin_inff();
          if (k0 + 32 + kvl > qabs) p1[r] = -__builtin_inff();
        }
      }

      // ---- online softmax, fully in-register ----
      float mt = p0[0];
      #pragma unroll
      for (int r = 1; r < 16; r++) mt = fmaxf(mt, p0[r]);
      #pragma unroll
      for (int r = 0; r < 16; r++) mt = fmaxf(mt, p1[r]);
      mt = cross_half_max(mt);
      float mnew = fmaxf(m_, mt);
      float f = __expf(m_ - mnew);
      m_ = mnew;
      float ls = 0.f;
      #pragma unroll
      for (int r = 0; r < 16; r++) { p0[r] = __expf(p0[r] - mnew); ls += p0[r]; }
      #pragma unroll
      for (int r = 0; r < 16; r++) { p1[r] = __expf(p1[r] - mnew); ls += p1[r]; }
      ls = cross_half_add(ls);
      l_ = l_ * f + ls;

      // ---- broadcast per-q rescale factor, rescale O ----
      if (lane < 32) f_lds[wave][lane] = f;
      f32x4 fr[4];
      #pragma unroll
      for (int i = 0; i < 4; i++)
        fr[i] = *(const f32x4*)&f_lds[wave][i * 8 + hi * 4];
      #pragma unroll
      for (int d = 0; d < 4; d++)
        #pragma unroll
        for (int r = 0; r < 16; r++) acc_o[d][r] *= fr[r >> 2][r & 3];

      // ---- O += P V : build A-frags (cvt_pk + permlane32_swap), 16 MFMA ----
      __builtin_amdgcn_s_setprio(1);
      #pragma unroll
      for (int ks = 0; ks < 4; ks++) {
        const f32x16 &pp = (ks < 2) ? p0 : p1;
        const int kk = (ks & 1) * 8;
        unsigned a0 = cvtpk_bf16(pp[kk + 0], pp[kk + 1]);
        unsigned b0 = cvtpk_bf16(pp[kk + 4], pp[kk + 5]);
        permswap32(a0, b0);               // a0 = word0, b0 = word2
        unsigned a1 = cvtpk_bf16(pp[kk + 2], pp[kk + 3]);
        unsigned b1 = cvtpk_bf16(pp[kk + 6], pp[kk + 7]);
        permswap32(a1, b1);               // a1 = word1, b1 = word3
        uint4v w; w[0] = a0; w[1] = a1; w[2] = b0; w[3] = b1;
        short8 af = __builtin_bit_cast(short8, w);
        #pragma unroll
        for (int db = 0; db < 4; db++) {
          int d  = db * 32 + l31;
          int ch = (ks * 2 + hi) ^ (d & 7);
          short8 vf = *(const short8*)(vb_ + d * 64 + ch * 8);
          acc_o[db] = __builtin_amdgcn_mfma_f32_32x32x16_bf16(af, vf, acc_o[db], 0, 0, 0);
        }
      }
      __builtin_amdgcn_s_setprio(0);
    }
    __syncthreads();   // readers done with buf[t&1]; stage(t+1) landed
  }

  // ---- normalize and write O ----
  if (lane < 32) f_lds[wave][lane] = 1.0f / l_;
  f32x4 lr[4];
  #pragma unroll
  for (int i = 0; i < 4; i++)
    lr[i] = *(const f32x4*)&f_lds[wave][i * 8 + hi * 4];
  #pragma unroll
  for (int db = 0; db < 4; db++)
    #pragma unroll
    for (int r = 0; r < 16; r++) {
      int row = qw + (r & 3) + 8 * (r >> 2) + 4 * hi;
      AO[(rowbase + row) * H_ + colbase + db * 32 + l31] =
          f2bf(acc_o[db][r] * lr[r >> 2][r & 3]);
    }
}

// ---------------------------------------------------------------------------
extern "C" void kernel_launch(void* const* d_in, const int* in_sizes, int n_in,
                              void* d_out, int out_size, void* d_ws, size_t ws_size,
                              hipStream_t stream)
{
  const float* x  = (const float*)d_in[0];
  // d_in[1] = mask (tril causal) — implemented analytically
  const float* Wq = (const float*)d_in[2];
  const float* Wk = (const float*)d_in[3];
  const float* Wv = (const float*)d_in[4];
  const float* Wo = (const float*)d_in[5];
  float* out = (float*)d_out;

  char* ws = (char*)d_ws;
  const size_t SZ = (size_t)ML_ * H_ * sizeof(short);  // 32 MiB
  short* Qb = (short*)(ws);
  short* Kb = (short*)(ws + SZ);
  short* Vb = (short*)(ws + 2 * SZ);
  short* xb = (short*)(ws + 3 * SZ);   // x bf16; dead after V-GEMM
  short* VT = xb;                      // V^T [bh][d][l], reuses xb region
  short* AO = Vb;                      // attn out, reuses Vb (dead after transpose)
  short* Wb = (short*)(ws + 4 * SZ);   // 8 MiB, reused per weight
  float* cosT = (float*)(ws + 4 * SZ + (size_t)H_ * H_ * sizeof(short));
  float* sinT = cosT + (size_t)L_ * 64;

  rope_table<<<512, 256, 0, stream>>>(cosT, sinT);

  cvt_bf16<<<ML_ * H_ / 8 / 256, 256, 0, stream>>>(x, xb, ML_ * H_ / 8);

  cvt_bf16<<<H_ * H_ / 8 / 256, 256, 0, stream>>>(Wq, Wb, H_ * H_ / 8);
  gemm256_bt<0><<<256, 512, 0, stream>>>(xb, Wb, Qb);
  cvt_bf16<<<H_ * H_ / 8 / 256, 256, 0, stream>>>(Wk, Wb, H_ * H_ / 8);
  gemm256_bt<0><<<256, 512, 0, stream>>>(xb, Wb, Kb);
  cvt_bf16<<<H_ * H_ / 8 / 256, 256, 0, stream>>>(Wv, Wb, H_ * H_ / 8);
  gemm256_bt<0><<<256, 512, 0, stream>>>(xb, Wb, Vb);

  // x (xb) is dead now: transpose V into its slot
  transpose_v<<<64 * 32 * 2, 256, 0, stream>>>(Vb, VT);

  rope_apply<<<dim3(ML_ * NH_ * 8 / 256, 2), 256, 0, stream>>>(Qb, Kb, cosT, sinT);

  flash_attn<<<512, 512, 0, stream>>>(Qb, Kb, VT, AO);

  cvt_bf16<<<H_ * H_ / 8 / 256, 256, 0, stream>>>(Wo, Wb, H_ * H_ / 8);
  gemm256_bt<1><<<256, 512, 0, stream>>>(AO, Wb, out);
}

// Round 6
// 446.275 us; speedup vs baseline: 3.6089x; 1.0355x over previous
//
#include <hip/hip_runtime.h>
#include <cstdint>
#include <cmath>

// Problem constants
#define B_   4
#define L_   2048
#define H_   2048
#define NH_  16
#define HD_  128
#define ML_  (B_*L_)   // 8192 rows total

using short8 = __attribute__((ext_vector_type(8))) short;
using f32x4  = __attribute__((ext_vector_type(4))) float;
using f32x16 = __attribute__((ext_vector_type(16))) float;
using uint4v = __attribute__((ext_vector_type(4))) unsigned;

__device__ inline short f2bf(float f){
  unsigned u = __builtin_bit_cast(unsigned, f);
  unsigned r = u + 0x7FFFu + ((u >> 16) & 1u);   // RNE
  return (short)(r >> 16);
}
__device__ inline float bf2f(short s){
  unsigned u = ((unsigned)(unsigned short)s) << 16;
  return __builtin_bit_cast(float, u);
}

// async global->LDS, 16B per lane, wave-uniform LDS base + lane*16
#define GLD16(gp, lp) __builtin_amdgcn_global_load_lds(                      \
    (const __attribute__((address_space(1))) void*)(gp),                     \
    (__attribute__((address_space(3))) void*)(lp), 16, 0, 0)

// pack 2 f32 -> 2 bf16 (RNE), dst.lo16 = lo, dst.hi16 = hi
__device__ inline unsigned cvtpk_bf16(float lo, float hi){
  unsigned d;
  asm("v_cvt_pk_bf16_f32 %0, %1, %2" : "=v"(d) : "v"(lo), "v"(hi));
  return d;
}
// NOTE: only safe when a and b are provably-distinct values (round-3 NaN:
// equal-valued operands can be register-coalesced into one VGPR).
__device__ inline void permswap32(unsigned &a, unsigned &b){
  asm volatile("v_permlane32_swap_b32 %0, %1" : "+v"(a), "+v"(b));
}
__device__ inline float cross_half_max(float x){
  return fmaxf(x, __shfl_xor(x, 32));
}
__device__ inline float cross_half_add(float x){
  return x + __shfl_xor(x, 32);
}

// ---------------------------------------------------------------------------
// RoPE cos/sin table: [2048][64] each, f32
// ---------------------------------------------------------------------------
__global__ void rope_table(float* __restrict__ cosT, float* __restrict__ sinT){
  int idx = blockIdx.x * 256 + threadIdx.x;
  if (idx >= L_ * 64) return;
  int l = idx >> 6, d = idx & 63;
  float invf = powf(10000.0f, -(float)d * (1.0f/64.0f));
  float fr = (float)l * invf;
  cosT[idx] = cosf(fr);
  sinT[idx] = sinf(fr);
}

// ---------------------------------------------------------------------------
// f32 -> bf16 elementwise (vectorized 8/thread)
// ---------------------------------------------------------------------------
__global__ __launch_bounds__(256)
void cvt_bf16(const float* __restrict__ in, short* __restrict__ out, int n8){
  int i = blockIdx.x * 256 + threadIdx.x;
  if (i >= n8) return;
  const float4* p = (const float4*)(in + (size_t)i * 8);
  float4 a = p[0], b = p[1];
  short8 s;
  s[0]=f2bf(a.x); s[1]=f2bf(a.y); s[2]=f2bf(a.z); s[3]=f2bf(a.w);
  s[4]=f2bf(b.x); s[5]=f2bf(b.y); s[6]=f2bf(b.z); s[7]=f2bf(b.w);
  *(short8*)(out + (size_t)i * 8) = s;
}

// 3 weights -> one packed bf16 buffer [6144][2048]
__global__ __launch_bounds__(256)
void cvt_w3(const float* __restrict__ W0, const float* __restrict__ W1,
            const float* __restrict__ W2, short* __restrict__ out){
  int i = blockIdx.x * 256 + threadIdx.x;     // 0 .. 3*H*H/8-1
  const int per = H_ * H_ / 8;
  const float* src; int j;
  if (i < per)            { src = W0; j = i; }
  else if (i < 2 * per)   { src = W1; j = i - per; }
  else                    { src = W2; j = i - 2 * per; }
  const float4* p = (const float4*)(src + (size_t)j * 8);
  float4 a = p[0], b = p[1];
  short8 s;
  s[0]=f2bf(a.x); s[1]=f2bf(a.y); s[2]=f2bf(a.z); s[3]=f2bf(a.w);
  s[4]=f2bf(b.x); s[5]=f2bf(b.y); s[6]=f2bf(b.z); s[7]=f2bf(b.w);
  *(short8*)(out + (size_t)i * 8) = s;
}

// ---------------------------------------------------------------------------
// GEMM 256x256 tile, counted-vmcnt deep pipeline (T3+T4).
//   QKV=0: C[8192,2048] = A @ B^T, 256 blocks (n per XCD).
//   QKV=1: B is packed [6144,2048] (Wq|Wk|Wv); 768 blocks; output routed to
//          C0/C1/C2 by n-tile (n_t>>3); n_t = xcd + 8*(i>>5) keeps each
//          XCD on few B panels.
//   LDS swizzle upgraded: slot = chunk ^ (r&3) ^ ((r>>2)&3) on BOTH the
//   pre-swizzled global source and the read side (rule #21) -> rows 4/8/12
//   apart no longer alias the same banks (was a 4-way conflict).
// ---------------------------------------------------------------------------
template<int QKV, int OUT_F32>
__global__ __launch_bounds__(512, 2)
void gemm256_bt(const short* __restrict__ A, const short* __restrict__ Bw,
                void* __restrict__ C0, void* __restrict__ C1,
                void* __restrict__ C2)
{
  constexpr int K = 2048, N = 2048;
  __shared__ short sA[4][256 * 32];      // 64 KiB
  __shared__ short sB[4][256 * 32];      // 64 KiB
  const int tid  = threadIdx.x;
  const int lane = tid & 63;
  const int wave = tid >> 6;
  const int wr = wave >> 2, wc = wave & 3;   // 2M x 4N wave grid
  const int ln = lane & 15, g = lane >> 4;

  const int blk = blockIdx.x;
  int n_t, m_t;
  if constexpr (QKV) { int i = blk >> 3; n_t = (blk & 7) + 8 * (i >> 5); m_t = i & 31; }
  else               { n_t = blk & 7;    m_t = blk >> 3; }
  const int m0 = m_t * 256;
  const int nb0 = n_t * 256;             // B-row base (packed rows for QKV)

  // staging geometry: 1024 16B-slots per (matrix, tile); 2 per thread
  const int u0 = wave * 64 + lane;           // 0..511   -> rows 0..127
  const int u1 = u0 + 512;                   // 512..1023-> rows 128..255
  const int r0 = u0 >> 2, c0 = (((u0 & 3) ^ (r0 & 3) ^ ((r0 >> 2) & 3))) * 8;
  const int r1 = u1 >> 2, c1 = (((u1 & 3) ^ (r1 & 3) ^ ((r1 >> 2) & 3))) * 8;

  f32x4 acc[8][4];
  #pragma unroll
  for (int m = 0; m < 8; m++)
    #pragma unroll
    for (int n = 0; n < 4; n++) acc[m][n] = {0.f, 0.f, 0.f, 0.f};

#define STAGE256(T) do {                                                     \
    const int _b = (T) & 3; const int _k = (T) * 32;                         \
    GLD16(A  + (size_t)(m0 + r0) * K + _k + c0, &sA[_b][wave * 512]);        \
    GLD16(A  + (size_t)(m0 + r1) * K + _k + c1, &sA[_b][4096 + wave * 512]); \
    GLD16(Bw + (size_t)(nb0 + r0) * K + _k + c0, &sB[_b][wave * 512]);       \
    GLD16(Bw + (size_t)(nb0 + r1) * K + _k + c1, &sB[_b][4096 + wave * 512]);\
  } while (0)

#define TILE256(T, VMN, PF) do {                                             \
    asm volatile("s_waitcnt vmcnt(" #VMN ")" ::: "memory");                  \
    __builtin_amdgcn_s_barrier();                                            \
    asm volatile("" ::: "memory");                                           \
    const short* _at = &sA[(T) & 3][0];                                      \
    const short* _bt = &sB[(T) & 3][0];                                      \
    short8 af[8], bfr[4];                                                    \
    const int _sl = (g ^ (ln & 3) ^ ((ln >> 2) & 3)) * 8;                    \
    _Pragma("unroll")                                                        \
    for (int m = 0; m < 8; m++)                                              \
      af[m] = *(const short8*)(_at + (wr * 128 + m * 16 + ln) * 32 + _sl);   \
    _Pragma("unroll")                                                        \
    for (int n = 0; n < 4; n++)                                              \
      bfr[n] = *(const short8*)(_bt + (wc * 64 + n * 16 + ln) * 32 + _sl);   \
    if (PF) STAGE256((T) + 3);                                               \
    __builtin_amdgcn_s_setprio(1);                                           \
    _Pragma("unroll")                                                        \
    for (int m = 0; m < 8; m++)                                              \
      _Pragma("unroll")                                                      \
      for (int n = 0; n < 4; n++)                                            \
        acc[m][n] = __builtin_amdgcn_mfma_f32_16x16x32_bf16(af[m], bfr[n],   \
                                                            acc[m][n], 0, 0, 0); \
    __builtin_amdgcn_s_setprio(0);                                           \
  } while (0)

  // prologue: 3 tiles in flight
  STAGE256(0); STAGE256(1); STAGE256(2);

  for (int t = 0; t < 61; ++t) TILE256(t, 8, true);   // prefetch t+3 = 3..63
  TILE256(61, 8, false);
  TILE256(62, 4, false);
  TILE256(63, 0, false);

#undef STAGE256
#undef TILE256

  // epilogue: C/D layout col=lane&15, row=(lane>>4)*4+reg
  void* Cp; int cb;
  if constexpr (QKV) {
    int w = n_t >> 3;
    Cp = (w == 0) ? C0 : (w == 1) ? C1 : C2;
    cb = (n_t & 7) * 256;
  } else { Cp = C0; cb = nb0; }
  #pragma unroll
  for (int m = 0; m < 8; m++)
    #pragma unroll
    for (int n = 0; n < 4; n++)
      #pragma unroll
      for (int r = 0; r < 4; r++) {
        int row = m0 + wr * 128 + m * 16 + g * 4 + r;
        int col = cb + wc * 64 + n * 16 + ln;
        float v = acc[m][n][r];
        if constexpr (OUT_F32) ((float*)Cp)[(size_t)row * N + col] = v;
        else                   ((short*)Cp)[(size_t)row * N + col] = f2bf(v);
      }
}

// ---------------------------------------------------------------------------
// RoPE apply, in place on bf16 Q (z=0, scaled by 1/sqrt(128)) and K (z=1).
// ---------------------------------------------------------------------------
__global__ __launch_bounds__(256)
void rope_apply(short* __restrict__ Qb, short* __restrict__ Kb,
                const float* __restrict__ cosT, const float* __restrict__ sinT)
{
  int idx = blockIdx.x * 256 + threadIdx.x;
  int z = blockIdx.y;
  short* ptr  = z ? Kb : Qb;
  float scale = z ? 1.0f : 0.08838834764831845f;
  int row = idx >> 7;
  int rem = idx & 127;
  int h = rem >> 3, ch = rem & 7;
  int l = row & (L_ - 1);
  short* base = ptr + (size_t)row * H_ + h * HD_ + ch * 8;
  short8 lo = *(short8*)base;
  short8 hi = *(short8*)(base + 64);
  const float* cp = cosT + l * 64 + ch * 8;
  const float* sp = sinT + l * 64 + ch * 8;
  short8 nlo, nhi;
  #pragma unroll
  for (int j = 0; j < 8; j++) {
    float c = cp[j], s = sp[j];
    float x0 = bf2f(lo[j]), x1 = bf2f(hi[j]);
    nlo[j] = f2bf((x0 * c - x1 * s) * scale);
    nhi[j] = f2bf((x1 * c + x0 * s) * scale);
  }
  *(short8*)base        = nlo;
  *(short8*)(base + 64) = nhi;
}

// ---------------------------------------------------------------------------
// V transpose: Vb [b,l,h*128+d]  ->  VT [bh][d][l]   (unchanged)
// ---------------------------------------------------------------------------
__global__ __launch_bounds__(256)
void transpose_v(const short* __restrict__ Vb, short* __restrict__ VT)
{
  __shared__ short t[64 * 64];
  const int blk = blockIdx.x;           // 4096 = 64 bh x 32 ltile x 2 dtile
  const int dt = blk & 1, lt = (blk >> 1) & 31, bh = blk >> 6;
  const int b = bh >> 4, h = bh & 15;
  const int l0 = lt * 64, d0 = dt * 64;
  const int tid = threadIdx.x;
  #pragma unroll
  for (int i = 0; i < 2; i++) {
    int u = tid + i * 256;
    int r = u >> 3, c = u & 7;
    short8 v = *(const short8*)(Vb + ((size_t)b * L_ + l0 + r) * H_ + h * HD_ + d0 + c * 8);
    *(short8*)&t[r * 64 + ((c ^ ((r >> 3) & 7)) << 3)] = v;
  }
  __syncthreads();
  #pragma unroll
  for (int i = 0; i < 2; i++) {
    int u = tid + i * 256;
    int d = u >> 3, lc = u & 7;
    short8 o;
    #pragma unroll
    for (int j = 0; j < 8; j++) {
      int l = lc * 8 + j;
      o[j] = t[l * 64 + (((d >> 3) ^ (lc & 7)) << 3) + (d & 7)];
    }
    *(short8*)(VT + ((size_t)bh * HD_ + d0 + d) * L_ + l0 + lc * 8) = o;
  }
}

// ---------------------------------------------------------------------------
// Flash attention, 8-wave 32x32 swapped-QK^T. Changes vs R5:
//  - LDS swizzle upgraded to f(r) = (r&7) ^ ((r>>3)&3): rows 8/16/24 apart
//    no longer alias the same banks (source + read sides, rule #21).
//    Read-side factor fsw = (l31&7) ^ ((l31>>3)&3) is identical for p0/p1
//    rows (r and r+32) and for all V d-blocks (d = db*32+l31).
//  - T13 defer-max (THR=8): skip O-rescale + f_lds round-trip when
//    __all(mt <= m_ + 8); P bounded by e^8 (bf16-safe), l_ is f32.
// ---------------------------------------------------------------------------
__global__ __launch_bounds__(512, 2)
void flash_attn(const short* __restrict__ Qb, const short* __restrict__ Kb,
                const short* __restrict__ VT, short* __restrict__ AO)
{
  __shared__ short lds_k[2][64 * 128];    // [kv][d-chunks swz]  32 KiB
  __shared__ short lds_v[2][128 * 64];    // [d][kv-chunks swz]  32 KiB
  __shared__ float f_lds[8][32];

  const int blk = blockIdx.x;             // 512 = 64 bh x 8 q-blocks
  int bh, j;
  if (blk < 256) { bh = blk & 63; j = 7 - (blk >> 6); }        // heavy first
  else           { int u = blk - 256; bh = u & 63; j = 3 - (u >> 6); } // light last
  const int q0 = j * 256;
  const int T  = 4 * j + 4;               // kv tiles for this q-block
  const int h = bh & 15, b = bh >> 4;
  const int tid = threadIdx.x, wave = tid >> 6, lane = tid & 63;
  const int hi = lane >> 5, l31 = lane & 31;
  const size_t rowbase = (size_t)b * L_;
  const int colbase = h * HD_;
  const short* Kbh  = Kb + rowbase * H_ + colbase;     // row stride H_
  const short* VTbh = VT + (size_t)bh * HD_ * L_;      // row stride L_
  const int qw = q0 + wave * 32;
  const int qabs = qw + l31;
  const int fsw = (l31 & 7) ^ ((l31 >> 3) & 3);        // read-side swizzle

  // Q fragments (B-operand): qf[c][j] = Q[qabs][c*16 + hi*8 + j]
  short8 qf[8];
  {
    const short* qp = Qb + (rowbase + qabs) * H_ + colbase + hi * 8;
    #pragma unroll
    for (int c = 0; c < 8; c++) qf[c] = *(const short8*)(qp + c * 16);
  }

  f32x16 acc_o[4];
  #pragma unroll
  for (int d = 0; d < 4; d++)
    #pragma unroll
    for (int r = 0; r < 16; r++) acc_o[d][r] = 0.f;
  float m_ = -__builtin_inff(), l_ = 0.f;

  // stage one KV tile into buffer bufi (all 8 waves cooperate)
  auto stage = [&](int k0s, int bufi) {
    #pragma unroll
    for (int i = 0; i < 2; i++) {
      int c = wave * 2 + i;               // 0..15, wave-uniform
      {
        int rt = c * 4 + (lane >> 4);                  // kv row in tile
        int cg = (lane & 15) ^ (rt & 7) ^ ((rt >> 3) & 3);
        const short* gp = Kbh + (size_t)(k0s + rt) * H_ + cg * 8;
        GLD16(gp, &lds_k[bufi][c * 512]);
      }
      {
        int rd = c * 8 + (lane >> 3);                  // head-dim row
        int cg = (lane & 7) ^ (rd & 7) ^ ((rd >> 3) & 3);
        const short* gp = VTbh + (size_t)rd * L_ + k0s + cg * 8;
        GLD16(gp, &lds_v[bufi][c * 512]);
      }
    }
  };

  stage(0, 0);
  __syncthreads();                        // vmcnt(0) drained: buf0 ready

  for (int t = 0; t < T; ++t) {
    const int k0 = t * 64;
    if (t + 1 < T) stage((t + 1) * 64, (t + 1) & 1);
    const short* kb_ = lds_k[t & 1];
    const short* vb_ = lds_v[t & 1];

    if (k0 <= qw + 31) {                  // wave-uniform active check
      // ---- S^T = K Q^T : 2 x (8-chain) 32x32x16 MFMA ----
      f32x16 p0, p1;
      #pragma unroll
      for (int r = 0; r < 16; r++) { p0[r] = 0.f; p1[r] = 0.f; }
      __builtin_amdgcn_s_setprio(1);
      #pragma unroll
      for (int c = 0; c < 8; c++) {
        int ch = (c * 2 + hi) ^ fsw;
        short8 kf0 = *(const short8*)(kb_ + l31 * 128 + ch * 8);
        short8 kf1 = *(const short8*)(kb_ + (32 + l31) * 128 + ch * 8);
        p0 = __builtin_amdgcn_mfma_f32_32x32x16_bf16(kf0, qf[c], p0, 0, 0, 0);
        p1 = __builtin_amdgcn_mfma_f32_32x32x16_bf16(kf1, qf[c], p1, 0, 0, 0);
      }
      __builtin_amdgcn_s_setprio(0);

      // ---- causal mask (<=2 tiles per wave hit this) ----
      if (k0 + 63 > qw) {
        #pragma unroll
        for (int r = 0; r < 16; r++) {
          int kvl = (r & 3) + 8 * (r >> 2) + 4 * hi;
          if (k0 + kvl > qabs)      p0[r] = -__builtin_inff();
          if (k0 + 32 + kvl > qabs) p1[r] = -__builtin_inff();
        }
      }

      // ---- online softmax, in-register, with defer-max (T13) ----
      float mt = p0[0];
      #pragma unroll
      for (int r = 1; r < 16; r++) mt = fmaxf(mt, p0[r]);
      #pragma unroll
      for (int r = 0; r < 16; r++) mt = fmaxf(mt, p1[r]);
      mt = cross_half_max(mt);
      if (!__all(mt <= m_ + 8.0f)) {
        float mnew = fmaxf(m_, mt);
        float f = __expf(m_ - mnew);
        m_ = mnew;
        l_ *= f;
        if (lane < 32) f_lds[wave][lane] = f;
        f32x4 fr[4];
        #pragma unroll
        for (int i = 0; i < 4; i++)
          fr[i] = *(const f32x4*)&f_lds[wave][i * 8 + hi * 4];
        #pragma unroll
        for (int d = 0; d < 4; d++)
          #pragma unroll
          for (int r = 0; r < 16; r++) acc_o[d][r] *= fr[r >> 2][r & 3];
      }
      float ls = 0.f;
      #pragma unroll
      for (int r = 0; r < 16; r++) { p0[r] = __expf(p0[r] - m_); ls += p0[r]; }
      #pragma unroll
      for (int r = 0; r < 16; r++) { p1[r] = __expf(p1[r] - m_); ls += p1[r]; }
      ls = cross_half_add(ls);
      l_ += ls;

      // ---- O += P V : build A-frags (cvt_pk + permlane32_swap), 16 MFMA ----
      __builtin_amdgcn_s_setprio(1);
      #pragma unroll
      for (int ks = 0; ks < 4; ks++) {
        const f32x16 &pp = (ks < 2) ? p0 : p1;
        const int kk = (ks & 1) * 8;
        unsigned a0 = cvtpk_bf16(pp[kk + 0], pp[kk + 1]);
        unsigned b0 = cvtpk_bf16(pp[kk + 4], pp[kk + 5]);
        permswap32(a0, b0);               // a0 = word0, b0 = word2
        unsigned a1 = cvtpk_bf16(pp[kk + 2], pp[kk + 3]);
        unsigned b1 = cvtpk_bf16(pp[kk + 6], pp[kk + 7]);
        permswap32(a1, b1);               // a1 = word1, b1 = word3
        uint4v w; w[0] = a0; w[1] = a1; w[2] = b0; w[3] = b1;
        short8 af = __builtin_bit_cast(short8, w);
        #pragma unroll
        for (int db = 0; db < 4; db++) {
          int d  = db * 32 + l31;
          int ch = (ks * 2 + hi) ^ fsw;
          short8 vf = *(const short8*)(vb_ + d * 64 + ch * 8);
          acc_o[db] = __builtin_amdgcn_mfma_f32_32x32x16_bf16(af, vf, acc_o[db], 0, 0, 0);
        }
      }
      __builtin_amdgcn_s_setprio(0);
    }
    __syncthreads();   // readers done with buf[t&1]; stage(t+1) landed
  }

  // ---- normalize and write O ----
  if (lane < 32) f_lds[wave][lane] = 1.0f / l_;
  f32x4 lr[4];
  #pragma unroll
  for (int i = 0; i < 4; i++)
    lr[i] = *(const f32x4*)&f_lds[wave][i * 8 + hi * 4];
  #pragma unroll
  for (int db = 0; db < 4; db++)
    #pragma unroll
    for (int r = 0; r < 16; r++) {
      int row = qw + (r & 3) + 8 * (r >> 2) + 4 * hi;
      AO[(rowbase + row) * H_ + colbase + db * 32 + l31] =
          f2bf(acc_o[db][r] * lr[r >> 2][r & 3]);
    }
}

// ---------------------------------------------------------------------------
extern "C" void kernel_launch(void* const* d_in, const int* in_sizes, int n_in,
                              void* d_out, int out_size, void* d_ws, size_t ws_size,
                              hipStream_t stream)
{
  const float* x  = (const float*)d_in[0];
  // d_in[1] = mask (tril causal) — implemented analytically
  const float* Wq = (const float*)d_in[2];
  const float* Wk = (const float*)d_in[3];
  const float* Wv = (const float*)d_in[4];
  const float* Wo = (const float*)d_in[5];
  float* out = (float*)d_out;

  char* ws = (char*)d_ws;
  const size_t SZ = (size_t)ML_ * H_ * sizeof(short);  // 32 MiB
  short* Qb = (short*)(ws);
  short* Kb = (short*)(ws + SZ);
  short* Vb = (short*)(ws + 2 * SZ);
  short* xb = (short*)(ws + 3 * SZ);   // x bf16; dead after QKV GEMM
  short* VT = xb;                      // V^T [bh][d][l], reuses xb region
  short* AO = Vb;                      // attn out, reuses Vb (dead after transpose)
  float* cosT = (float*)(ws + 4 * SZ);
  float* sinT = cosT + (size_t)L_ * 64;
  short* Wb = (short*)(ws + 4 * SZ + (size_t)(1 << 20));  // up to 24 MiB packed
  const size_t NEED_FUSED = 4 * SZ + (1 << 20) + (size_t)3 * H_ * H_ * sizeof(short);
  const bool fused = ws_size >= NEED_FUSED;

  rope_table<<<512, 256, 0, stream>>>(cosT, sinT);

  cvt_bf16<<<ML_ * H_ / 8 / 256, 256, 0, stream>>>(x, xb, ML_ * H_ / 8);

  if (fused) {
    cvt_w3<<<3 * H_ * H_ / 8 / 256, 256, 0, stream>>>(Wq, Wk, Wv, Wb);
    gemm256_bt<1, 0><<<768, 512, 0, stream>>>(xb, Wb, Qb, Kb, Vb);
  } else {
    cvt_bf16<<<H_ * H_ / 8 / 256, 256, 0, stream>>>(Wq, Wb, H_ * H_ / 8);
    gemm256_bt<0, 0><<<256, 512, 0, stream>>>(xb, Wb, Qb, Qb, Qb);
    cvt_bf16<<<H_ * H_ / 8 / 256, 256, 0, stream>>>(Wk, Wb, H_ * H_ / 8);
    gemm256_bt<0, 0><<<256, 512, 0, stream>>>(xb, Wb, Kb, Kb, Kb);
    cvt_bf16<<<H_ * H_ / 8 / 256, 256, 0, stream>>>(Wv, Wb, H_ * H_ / 8);
    gemm256_bt<0, 0><<<256, 512, 0, stream>>>(xb, Wb, Vb, Vb, Vb);
  }

  // x (xb) is dead now: transpose V into its slot
  transpose_v<<<64 * 32 * 2, 256, 0, stream>>>(Vb, VT);

  rope_apply<<<dim3(ML_ * NH_ * 8 / 256, 2), 256, 0, stream>>>(Qb, Kb, cosT, sinT);

  flash_attn<<<512, 512, 0, stream>>>(Qb, Kb, VT, AO);

  cvt_bf16<<<H_ * H_ / 8 / 256, 256, 0, stream>>>(Wo, Wb, H_ * H_ / 8);
  gemm256_bt<0, 1><<<256, 512, 0, stream>>>(AO, Wb, out, out, out);
}